// Round 5
// baseline (19308.890 us; speedup 1.0000x reference)
//
#include <hip/hip_runtime.h>

#define HID 768
#define EMB 512
#define NG  64
#define FIN 5
#define NL  16
#define CB  384   // column block width (HID/2)

typedef _Float16 f16;
typedef f16   f16x4 __attribute__((ext_vector_type(4)));
typedef f16   f16x8 __attribute__((ext_vector_type(8)));
typedef float f32x4 __attribute__((ext_vector_type(4)));

// ---------------- CSR build ----------------
__global__ void count_deg_k(const int* __restrict__ ei, int* __restrict__ deg, int E) {
    int e = blockIdx.x * 256 + threadIdx.x;
    if (e < E) atomicAdd(&deg[ei[E + e]], 1);
}

__global__ void count_nodes_k(const int* __restrict__ batch, int* __restrict__ gcnt, int n) {
    int i = blockIdx.x * 256 + threadIdx.x;
    if (i < n) atomicAdd(&gcnt[batch[i]], 1);
}

__global__ void scan_rowptr_k(const int* __restrict__ deg, int* __restrict__ rp,
                              int* __restrict__ cur, int n) {
    __shared__ int wsum[16];
    __shared__ int carry;
    int t = threadIdx.x, lane = t & 63, w = t >> 6;
    if (t == 0) carry = 0;
    __syncthreads();
    for (int base = 0; base < n; base += 4096) {
        int v[4]; int s = 0;
        #pragma unroll
        for (int q = 0; q < 4; ++q) { int i = base + t * 4 + q; v[q] = (i < n) ? deg[i] : 0; s += v[q]; }
        int tot = s;
        int sc = tot;
        #pragma unroll
        for (int off = 1; off < 64; off <<= 1) { int u = __shfl_up(sc, off); if (lane >= off) sc += u; }
        if (lane == 63) wsum[w] = sc;
        __syncthreads();
        if (t < 16) {
            int xw = wsum[t];
            #pragma unroll
            for (int off = 1; off < 16; off <<= 1) { int u = __shfl_up(xw, off); if (t >= off) xw += u; }
            wsum[t] = xw;
        }
        __syncthreads();
        int woff = (w > 0) ? wsum[w - 1] : 0;
        int excl = carry + woff + sc - tot;
        #pragma unroll
        for (int q = 0; q < 4; ++q) { int i = base + t * 4 + q; if (i < n) { rp[i] = excl; cur[i] = excl; } excl += v[q]; }
        __syncthreads();
        if (t == 0) carry += wsum[15];
        __syncthreads();
    }
    if (t == 0) rp[n] = carry;
}

__global__ void scatter_k(const int* __restrict__ ei, int* __restrict__ cur,
                          int* __restrict__ csr, int E) {
    int e = blockIdx.x * 256 + threadIdx.x;
    if (e < E) { int d = ei[E + e]; int pos = atomicAdd(&cur[d], 1); csr[pos] = ei[e]; }
}

// canonicalize neighbor order (atomic scatter order varies call-to-call)
__global__ void sort_csr_k(const int* __restrict__ rp, int* __restrict__ csr, int n) {
    int i = blockIdx.x * 256 + threadIdx.x;
    if (i >= n) return;
    int e0 = rp[i], e1 = rp[i + 1];
    for (int a = e0 + 1; a < e1; ++a) {
        int v = csr[a];
        int b = a - 1;
        while (b >= e0 && csr[b] > v) { csr[b + 1] = csr[b]; --b; }
        csr[b + 1] = v;
    }
}

__global__ void gscan_k(const int* __restrict__ gcnt, int* __restrict__ goff) {
    if (threadIdx.x == 0) {
        int s = 0;
        for (int g = 0; g < NG; ++g) { goff[g] = s; s += gcnt[g]; }
        goff[NG] = s;
    }
}

// ---- per-layer weight convert: W[k][n] fp32 -> wt[z][n][k] fp16 * 64 ----
__global__ void convert_layer_k(const float* __restrict__ Wa, const float* __restrict__ Wb,
                                f16* __restrict__ wt) {
    __shared__ float tile[64][65];
    const float* src = blockIdx.z ? Wb : Wa;
    f16* dst = wt + (size_t)blockIdx.z * HID * HID;
    int k0 = blockIdx.x * 64, n0 = blockIdx.y * 64;
    int t = threadIdx.x;
    #pragma unroll 4
    for (int i = 0; i < 16; ++i) {
        int r = (t >> 6) + i * 4;
        tile[r][t & 63] = src[(size_t)(k0 + r) * HID + n0 + (t & 63)];
    }
    __syncthreads();
    #pragma unroll 4
    for (int i = 0; i < 16; ++i) {
        int r = (t >> 6) + i * 4;
        dst[(size_t)(n0 + r) * HID + k0 + (t & 63)] = (f16)(tile[t & 63][r] * 64.0f);
    }
}

// ---- layer-0 folding ----
__global__ void make_wp1_k(const float* __restrict__ Wp, const float* __restrict__ bp,
                           const float* __restrict__ W1_0, float* __restrict__ wp1) {
    int nn = blockIdx.x * 256 + threadIdx.x;
    if (nn >= HID) return;
    float acc[6] = {0, 0, 0, 0, 0, 0};
    for (int j = 0; j < HID; ++j) {
        float wj = W1_0[(size_t)j * HID + nn];
        #pragma unroll
        for (int k = 0; k < FIN; ++k) acc[k] += Wp[k * HID + j] * wj;
        acc[5] += bp[j] * wj;
    }
    #pragma unroll
    for (int k = 0; k < 6; ++k) wp1[k * HID + nn] = acc[k];
}

__device__ __forceinline__ void row_scale(float amax, float& sc, float& rs) {
    int ex = 10;
    if (amax > 0.0f) frexpf(amax, &ex);
    int sh = 10 - ex;
    sh = sh > 120 ? 120 : (sh < -120 ? -120 : sh);
    sc = ldexpf(1.0f, sh);
    rs = ldexpf(1.0f, -sh);
}

// ---- fused layer0: z = relu(xagg@wp1 + (deg+1)*bpW1 + b1_0); writes column-block bufs ----
__global__ __launch_bounds__(256) void fused_l0_k(
    const float* __restrict__ x, const int* __restrict__ rp, const int* __restrict__ csr,
    const float* __restrict__ wp1, const float* __restrict__ b1_0,
    f16* __restrict__ hx, f16* __restrict__ hy, float* __restrict__ rs_out, int nreal) {
    __shared__ float w[7 * HID];
    for (int idx = threadIdx.x; idx < 7 * HID; idx += 256)
        w[idx] = (idx < 6 * HID) ? wp1[idx] : b1_0[idx - 6 * HID];
    __syncthreads();
    int node = blockIdx.x * 4 + (threadIdx.x >> 6);
    int lane = threadIdx.x & 63;
    f16* orow = (lane < 32) ? (hx + (size_t)node * CB + lane * 12)
                            : (hy + (size_t)node * CB + (lane - 32) * 12);
    if (node >= nreal) {
        #pragma unroll
        for (int t = 0; t < 12; ++t) orow[t] = (f16)0.0f;
        if (lane == 0) rs_out[node] = 1.0f;
        return;
    }
    int e0 = rp[node], e1 = rp[node + 1];
    float xa[FIN];
    #pragma unroll
    for (int k = 0; k < FIN; ++k) xa[k] = x[(size_t)node * FIN + k];
    for (int e = e0; e < e1; ++e) {
        int j = csr[e];
        #pragma unroll
        for (int k = 0; k < FIN; ++k) xa[k] += x[(size_t)j * FIN + k];
    }
    float dp1 = (float)(e1 - e0 + 1);
    float a[12];
    #pragma unroll
    for (int t = 0; t < 12; ++t) {
        int c = lane * 12 + t;
        float v = w[5 * HID + c] * dp1 + w[6 * HID + c];
        #pragma unroll
        for (int k = 0; k < FIN; ++k) v += xa[k] * w[k * HID + c];
        a[t] = fmaxf(v, 0.0f);
    }
    float amax = 0.0f;
    #pragma unroll
    for (int t = 0; t < 12; ++t) amax = fmaxf(amax, fabsf(a[t]));
    #pragma unroll
    for (int off = 32; off; off >>= 1) amax = fmaxf(amax, __shfl_xor(amax, off));
    float sc, rs;
    row_scale(amax, sc, rs);
    if (lane == 0) rs_out[node] = rs;
    #pragma unroll
    for (int t = 0; t < 12; ++t) orow[t] = (f16)(a[t] * sc);
}

// ---- aggscale: fresh per-row output scale from recorded per-row real amax ----
__global__ void aggscale_k(const float* __restrict__ amaxR, const int* __restrict__ rp,
                           const int* __restrict__ csr, float* __restrict__ rsOut,
                           int nreal, int npad) {
    int i = blockIdx.x * 256 + threadIdx.x;
    if (i >= npad) return;
    if (i >= nreal) { rsOut[i] = 1.0f; return; }
    float M = amaxR[i];
    for (int e = rp[i]; e < rp[i + 1]; ++e) M = fmaxf(M, amaxR[csr[e]]);
    float r = 1.0f;
    if (M > 0.0f) {
        int ex; frexpf(M, &ex);
        int sh = ex - 9;                      // M / 2^sh in [256,512)
        sh = sh > 120 ? 120 : (sh < -120 ? -120 : sh);
        r = ldexpf(1.0f, sh);
    }
    rsOut[i] = r;
}

// ---- aggcol: one column block. out = (sum_{j in {i} u N(i)} src[j]*rsEff[j]) / rsOut[i] ----
__global__ __launch_bounds__(256) void aggcol_k(
    const f16* __restrict__ src, f16* __restrict__ dst,
    const float* __restrict__ rsIn, float inShift,
    const float* __restrict__ rsOut,
    const int* __restrict__ rp, const int* __restrict__ csr, int nreal) {
    int node = blockIdx.x * 8 + (threadIdx.x >> 5);
    int l = threadIdx.x & 31;
    f16* orow = dst + (size_t)node * CB + l * 12;
    if (node >= nreal) {
        #pragma unroll
        for (int t = 0; t < 12; ++t) orow[t] = (f16)0.0f;
        return;
    }
    float invOut = 1.0f / rsOut[node];
    float a[12];
    {
        float f = rsIn[node] * inShift * invOut;
        const f16x4* p = (const f16x4*)(src + (size_t)node * CB + l * 12);
        f16x4 v0 = p[0], v1 = p[1], v2 = p[2];
        #pragma unroll
        for (int t = 0; t < 4; ++t) {
            a[t] = (float)v0[t] * f; a[4 + t] = (float)v1[t] * f; a[8 + t] = (float)v2[t] * f;
        }
    }
    int e0 = rp[node], e1 = rp[node + 1];
    for (int e = e0; e < e1; ++e) {
        int j = csr[e];
        float f = rsIn[j] * inShift * invOut;
        const f16x4* p = (const f16x4*)(src + (size_t)j * CB + l * 12);
        f16x4 v0 = p[0], v1 = p[1], v2 = p[2];
        #pragma unroll
        for (int t = 0; t < 4; ++t) {
            a[t] += (float)v0[t] * f; a[4 + t] += (float)v1[t] * f; a[8 + t] += (float)v2[t] * f;
        }
    }
    f16x4 o0, o1, o2;
    #pragma unroll
    for (int t = 0; t < 4; ++t) {
        o0[t] = (f16)a[t]; o1[t] = (f16)a[4 + t]; o2[t] = (f16)a[8 + t];
    }
    f16x4* op = (f16x4*)orow;
    op[0] = o0; op[1] = o1; op[2] = o2;
}

// ---- in-place row-block GEMM: rows r0..r0+31 of [bx|by] -> relu((A@W)+b), overwritten.
// A staged to LDS (padded stride 776 -> conflict-free b128). B streamed from L2-resident wt.
// Output scale = rs[row]*shiftIn*8; epilogue records per-row real amax.
__global__ __launch_bounds__(256) void gemm_inplace_k(
    f16* __restrict__ bx, f16* __restrict__ by,
    const float* __restrict__ rs, float shiftIn,
    const f16* __restrict__ wt, const float* __restrict__ bias,
    float* __restrict__ amaxOut) {
    __shared__ f16 As[32 * 776];
    __shared__ float amLds[4 * 32];
    const int tid = threadIdx.x;
    const int r0 = blockIdx.x * 32;

    {
        const f16* src0 = bx + (size_t)r0 * CB;
        const f16* src1 = by + (size_t)r0 * CB;
        #pragma unroll
        for (int i = 0; i < 6; ++i) {
            int q = tid + 256 * i;            // 0..1535
            int row = q / 48, c8 = q % 48;
            f16x8 v0 = *(const f16x8*)(src0 + row * CB + c8 * 8);
            *(f16x8*)(&As[row * 776 + c8 * 8]) = v0;
            f16x8 v1 = *(const f16x8*)(src1 + row * CB + c8 * 8);
            *(f16x8*)(&As[row * 776 + CB + c8 * 8]) = v1;
        }
    }
    __syncthreads();

    const int lane = tid & 63;
    const int wid = tid >> 6;
    const int l15 = lane & 15, l4 = lane >> 4;

    float rinv[2][4], rEff8[2][4];
    #pragma unroll
    for (int rg = 0; rg < 2; ++rg)
        #pragma unroll
        for (int reg = 0; reg < 4; ++reg) {
            int row = r0 + rg * 16 + l4 * 4 + reg;
            float rv = rs[row] * shiftIn * 8.0f;
            rEff8[rg][reg] = rv;
            rinv[rg][reg] = 1.0f / rv;
        }
    float am[2][4] = {{0, 0, 0, 0}, {0, 0, 0, 0}};

    for (int ntq = 0; ntq < 3; ++ntq) {
        const int n0 = (wid * 3 + ntq) * 64;
        f32x4 acc[2][4];
        #pragma unroll
        for (int rg = 0; rg < 2; ++rg)
            #pragma unroll
            for (int ns = 0; ns < 4; ++ns) acc[rg][ns] = (f32x4){0.f, 0.f, 0.f, 0.f};
        for (int k = 0; k < HID; k += 32) {
            f16x8 af[2], bf[4];
            #pragma unroll
            for (int rg = 0; rg < 2; ++rg)
                af[rg] = *(const f16x8*)(&As[(rg * 16 + l15) * 776 + k + l4 * 8]);
            #pragma unroll
            for (int ns = 0; ns < 4; ++ns)
                bf[ns] = *(const f16x8*)(wt + (size_t)(n0 + ns * 16 + l15) * HID + k + l4 * 8);
            #pragma unroll
            for (int rg = 0; rg < 2; ++rg)
                #pragma unroll
                for (int ns = 0; ns < 4; ++ns)
                    acc[rg][ns] = __builtin_amdgcn_mfma_f32_16x16x32_f16(af[rg], bf[ns], acc[rg][ns], 0, 0, 0);
        }
        #pragma unroll
        for (int ns = 0; ns < 4; ++ns) {
            int col = n0 + ns * 16 + l15;
            float bcol = bias[col];
            #pragma unroll
            for (int rg = 0; rg < 2; ++rg) {
                #pragma unroll
                for (int reg = 0; reg < 4; ++reg) {
                    int row = r0 + rg * 16 + l4 * 4 + reg;
                    float v = acc[rg][ns][reg] * (1.0f / 512.0f) + bcol * rinv[rg][reg];
                    v = fmaxf(v, 0.0f);
                    am[rg][reg] = fmaxf(am[rg][reg], v);
                    f16 h = (f16)v;
                    if (col < CB) bx[(size_t)row * CB + col] = h;
                    else          by[(size_t)row * CB + col - CB] = h;
                }
            }
        }
    }
    // per-row amax: reduce across the 16 lanes sharing rows, stash per-wave, then cross-wave
    #pragma unroll
    for (int rg = 0; rg < 2; ++rg)
        #pragma unroll
        for (int reg = 0; reg < 4; ++reg) {
            float a = am[rg][reg];
            #pragma unroll
            for (int off = 1; off < 16; off <<= 1) a = fmaxf(a, __shfl_xor(a, off));
            am[rg][reg] = a;
        }
    if (l15 == 0) {
        #pragma unroll
        for (int rg = 0; rg < 2; ++rg)
            #pragma unroll
            for (int reg = 0; reg < 4; ++reg)
                amLds[wid * 32 + rg * 16 + l4 * 4 + reg] = am[rg][reg];
    }
    __syncthreads();
    if (tid < 32) {
        float m = fmaxf(fmaxf(amLds[tid], amLds[32 + tid]),
                        fmaxf(amLds[64 + tid], amLds[96 + tid]));
        amaxOut[r0 + tid] = m * (rs[r0 + tid] * shiftIn * 8.0f);
    }
}

// ---- pooling: deterministic per-graph serial sum over column blocks ----
__global__ __launch_bounds__(256) void pool_k(const f16* __restrict__ hx, const f16* __restrict__ hy,
                                              const float* __restrict__ rs, float shift,
                                              const int* __restrict__ goff, float* __restrict__ pooled) {
    int g = blockIdx.x, c = blockIdx.y;
    int t = threadIdx.x;
    int col = c * 256 + t;
    const f16* base; int cc;
    if (col < CB) { base = hx; cc = col; } else { base = hy; cc = col - CB; }
    int i0 = goff[g], i1 = goff[g + 1];
    float a = 0.0f;
    for (int i = i0; i < i1; ++i)
        a += (float)base[(size_t)i * CB + cc] * rs[i];
    pooled[g * HID + col] = a * shift;
}

__global__ __launch_bounds__(512) void final_mm_k(const float* __restrict__ pooled,
                                                  const int* __restrict__ goff,
                                                  const float* __restrict__ Wf,
                                                  const float* __restrict__ bf,
                                                  float* __restrict__ out) {
    __shared__ float ps[HID];
    int g = blockIdx.x;
    int t = threadIdx.x;
    float inv = 1.0f / fmaxf((float)(goff[g + 1] - goff[g]), 1.0f);
    for (int k = t; k < HID; k += 512) ps[k] = pooled[g * HID + k] * inv;
    __syncthreads();
    float acc = bf[t];
    for (int k = 0; k < HID; ++k) acc += ps[k] * Wf[(size_t)k * EMB + t];
    out[(size_t)g * EMB + t] = acc;
}

__global__ void sentinel_k(float* __restrict__ out, int n, float v) {
    int i = blockIdx.x * 256 + threadIdx.x;
    if (i < n) out[i] = v;
}

// ---------------- launch ----------------
extern "C" void kernel_launch(void* const* d_in, const int* in_sizes, int n_in,
                              void* d_out, int out_size, void* d_ws, size_t ws_size,
                              hipStream_t stream) {
    const float* x    = (const float*)d_in[0];
    const int*   ei   = (const int*)d_in[1];
    const int*   batch= (const int*)d_in[2];
    const float* Wp   = (const float*)d_in[3];
    const float* bp   = (const float*)d_in[4];
    const float* W1   = (const float*)d_in[5];
    const float* b1   = (const float*)d_in[6];
    const float* W2   = (const float*)d_in[7];
    const float* b2   = (const float*)d_in[8];
    const float* Wf   = (const float*)d_in[9];
    const float* bf   = (const float*)d_in[10];
    float* out = (float*)d_out;

    const int nreal = in_sizes[0] / FIN;       // 100000
    const int E     = in_sizes[1] / 2;         // 200000
    const int npad  = ((nreal + 127) / 128) * 128;   // 100224 (mult of 32)

    char* p = (char*)d_ws;
    auto alloc = [&](size_t bytes) -> char* {
        char* r = p; p += (bytes + 511) & ~(size_t)511; return r;
    };
    f16*   P0   = (f16*)  alloc((size_t)npad * CB * sizeof(f16));
    f16*   P1   = (f16*)  alloc((size_t)npad * CB * sizeof(f16));
    f16*   P2   = (f16*)  alloc((size_t)npad * CB * sizeof(f16));
    f16*   wt   = (f16*)  alloc((size_t)2 * HID * HID * sizeof(f16));
    float* rsA  = (float*)alloc((size_t)npad * sizeof(float));
    float* rsB  = (float*)alloc((size_t)npad * sizeof(float));
    float* amaxR= (float*)alloc((size_t)npad * sizeof(float));
    int*   rp   = (int*)  alloc((size_t)(npad + 1) * sizeof(int));
    int*   csr  = (int*)  alloc((size_t)E * sizeof(int));
    float* wp1  = (float*)alloc((size_t)6 * HID * sizeof(float));
    int*   goff = (int*)  alloc((size_t)(NG + 1) * sizeof(int));
    float* pooled = (float*)alloc((size_t)NG * HID * sizeof(float));
    char*  zstart = p;
    int*   deg  = (int*)  alloc((size_t)npad * sizeof(int));
    int*   cur  = (int*)  alloc((size_t)npad * sizeof(int));
    int*   gcnt = (int*)  alloc((size_t)NG * sizeof(int));
    size_t zbytes = (size_t)(p - zstart);
    size_t need  = (size_t)(p - (char*)d_ws);

    if (need > ws_size) {
        sentinel_k<<<(out_size + 255) / 256, 256, 0, stream>>>(out, out_size, (float)(ws_size >> 20));
        return;
    }

    hipMemsetAsync(zstart, 0, zbytes, stream);

    count_deg_k  <<<(E + 255) / 256, 256, 0, stream>>>(ei, deg, E);
    count_nodes_k<<<(nreal + 255) / 256, 256, 0, stream>>>(batch, gcnt, nreal);
    scan_rowptr_k<<<1, 1024, 0, stream>>>(deg, rp, cur, nreal);
    scatter_k    <<<(E + 255) / 256, 256, 0, stream>>>(ei, cur, csr, E);
    sort_csr_k   <<<(nreal + 255) / 256, 256, 0, stream>>>(rp, csr, nreal);
    gscan_k      <<<1, 64, 0, stream>>>(gcnt, goff);

    make_wp1_k<<<(HID + 255) / 256, 256, 0, stream>>>(Wp, bp, W1, wp1);

    f16 *X0 = P0, *X1 = P1, *S = P2;
    fused_l0_k<<<npad / 4, 256, 0, stream>>>(x, rp, csr, wp1, b1, X0, X1, rsA, nreal);

    // layer 0 second matmul (W2[0]), in-place on (X0,X1); records amaxR
    convert_layer_k<<<dim3(HID / 64, HID / 64, 2), 256, 0, stream>>>(W1, W2, wt);
    gemm_inplace_k<<<npad / 32, 256, 0, stream>>>(X0, X1, rsA, 1.0f,
                                                  wt + (size_t)HID * HID, b2, amaxR);
    float* rcur = rsA;
    float  shift = 8.0f;   // h scale = rcur * shift

    for (int l = 1; l < NL; ++l) {
        convert_layer_k<<<dim3(HID / 64, HID / 64, 2), 256, 0, stream>>>(
            W1 + (size_t)l * HID * HID, W2 + (size_t)l * HID * HID, wt);
        float* rnew = (rcur == rsA) ? rsB : rsA;
        aggscale_k<<<(npad + 255) / 256, 256, 0, stream>>>(amaxR, rp, csr, rnew, nreal, npad);
        aggcol_k<<<npad / 8, 256, 0, stream>>>(X0, S,  rcur, shift, rnew, rp, csr, nreal);
        aggcol_k<<<npad / 8, 256, 0, stream>>>(X1, X0, rcur, shift, rnew, rp, csr, nreal);
        { f16* t0 = S; S = X1; X1 = X0; X0 = t0; }   // AGG now in (X0,X1), scale rnew
        gemm_inplace_k<<<npad / 32, 256, 0, stream>>>(X0, X1, rnew, 1.0f,
                                                      wt, b1 + (size_t)l * HID, amaxR);
        gemm_inplace_k<<<npad / 32, 256, 0, stream>>>(X0, X1, rnew, 8.0f,
                                                      wt + (size_t)HID * HID, b2 + (size_t)l * HID, amaxR);
        rcur = rnew;
        shift = 64.0f;
    }

    pool_k<<<dim3(NG, HID / 256), 256, 0, stream>>>(X0, X1, rcur, shift, goff, pooled);
    final_mm_k<<<NG, 512, 0, stream>>>(pooled, goff, Wf, bf, out);
}

// Round 6
// 10380.868 us; speedup vs baseline: 1.8600x; 1.8600x over previous
//
#include <hip/hip_runtime.h>

#define HID 768
#define EMB 512
#define NG  64
#define FIN 5
#define NL  16
#define CB  384   // column block width (HID/2)

typedef _Float16 f16;
typedef f16   f16x4 __attribute__((ext_vector_type(4)));
typedef f16   f16x8 __attribute__((ext_vector_type(8)));
typedef float f32x4 __attribute__((ext_vector_type(4)));

// ---------------- CSR build ----------------
__global__ void count_deg_k(const int* __restrict__ ei, int* __restrict__ deg, int E) {
    int e = blockIdx.x * 256 + threadIdx.x;
    if (e < E) atomicAdd(&deg[ei[E + e]], 1);
}

__global__ void count_nodes_k(const int* __restrict__ batch, int* __restrict__ gcnt, int n) {
    int i = blockIdx.x * 256 + threadIdx.x;
    if (i < n) atomicAdd(&gcnt[batch[i]], 1);
}

__global__ void scan_rowptr_k(const int* __restrict__ deg, int* __restrict__ rp,
                              int* __restrict__ cur, int n) {
    __shared__ int wsum[16];
    __shared__ int carry;
    int t = threadIdx.x, lane = t & 63, w = t >> 6;
    if (t == 0) carry = 0;
    __syncthreads();
    for (int base = 0; base < n; base += 4096) {
        int v[4]; int s = 0;
        #pragma unroll
        for (int q = 0; q < 4; ++q) { int i = base + t * 4 + q; v[q] = (i < n) ? deg[i] : 0; s += v[q]; }
        int tot = s;
        int sc = tot;
        #pragma unroll
        for (int off = 1; off < 64; off <<= 1) { int u = __shfl_up(sc, off); if (lane >= off) sc += u; }
        if (lane == 63) wsum[w] = sc;
        __syncthreads();
        if (t < 16) {
            int xw = wsum[t];
            #pragma unroll
            for (int off = 1; off < 16; off <<= 1) { int u = __shfl_up(xw, off); if (t >= off) xw += u; }
            wsum[t] = xw;
        }
        __syncthreads();
        int woff = (w > 0) ? wsum[w - 1] : 0;
        int excl = carry + woff + sc - tot;
        #pragma unroll
        for (int q = 0; q < 4; ++q) { int i = base + t * 4 + q; if (i < n) { rp[i] = excl; cur[i] = excl; } excl += v[q]; }
        __syncthreads();
        if (t == 0) carry += wsum[15];
        __syncthreads();
    }
    if (t == 0) rp[n] = carry;
}

__global__ void scatter_k(const int* __restrict__ ei, int* __restrict__ cur,
                          int* __restrict__ csr, int E) {
    int e = blockIdx.x * 256 + threadIdx.x;
    if (e < E) { int d = ei[E + e]; int pos = atomicAdd(&cur[d], 1); csr[pos] = ei[e]; }
}

// canonicalize neighbor order (atomic scatter order varies call-to-call)
__global__ void sort_csr_k(const int* __restrict__ rp, int* __restrict__ csr, int n) {
    int i = blockIdx.x * 256 + threadIdx.x;
    if (i >= n) return;
    int e0 = rp[i], e1 = rp[i + 1];
    for (int a = e0 + 1; a < e1; ++a) {
        int v = csr[a];
        int b = a - 1;
        while (b >= e0 && csr[b] > v) { csr[b + 1] = csr[b]; --b; }
        csr[b + 1] = v;
    }
}

__global__ void gscan_k(const int* __restrict__ gcnt, int* __restrict__ goff) {
    if (threadIdx.x == 0) {
        int s = 0;
        for (int g = 0; g < NG; ++g) { goff[g] = s; s += gcnt[g]; }
        goff[NG] = s;
    }
}

// ---- per-layer weight convert: W[k][n] fp32 -> wt[z][n][k] fp16 * 64 ----
__global__ void convert_layer_k(const float* __restrict__ Wa, const float* __restrict__ Wb,
                                f16* __restrict__ wt) {
    __shared__ float tile[64][65];
    const float* src = blockIdx.z ? Wb : Wa;
    f16* dst = wt + (size_t)blockIdx.z * HID * HID;
    int k0 = blockIdx.x * 64, n0 = blockIdx.y * 64;
    int t = threadIdx.x;
    #pragma unroll 4
    for (int i = 0; i < 16; ++i) {
        int r = (t >> 6) + i * 4;
        tile[r][t & 63] = src[(size_t)(k0 + r) * HID + n0 + (t & 63)];
    }
    __syncthreads();
    #pragma unroll 4
    for (int i = 0; i < 16; ++i) {
        int r = (t >> 6) + i * 4;
        dst[(size_t)(n0 + r) * HID + k0 + (t & 63)] = (f16)(tile[t & 63][r] * 64.0f);
    }
}

// ---- layer-0 folding ----
__global__ void make_wp1_k(const float* __restrict__ Wp, const float* __restrict__ bp,
                           const float* __restrict__ W1_0, float* __restrict__ wp1) {
    int nn = blockIdx.x * 256 + threadIdx.x;
    if (nn >= HID) return;
    float acc[6] = {0, 0, 0, 0, 0, 0};
    for (int j = 0; j < HID; ++j) {
        float wj = W1_0[(size_t)j * HID + nn];
        #pragma unroll
        for (int k = 0; k < FIN; ++k) acc[k] += Wp[k * HID + j] * wj;
        acc[5] += bp[j] * wj;
    }
    #pragma unroll
    for (int k = 0; k < 6; ++k) wp1[k * HID + nn] = acc[k];
}

__device__ __forceinline__ void row_scale(float amax, float& sc, float& rs) {
    int ex = 10;
    if (amax > 0.0f) frexpf(amax, &ex);
    int sh = 10 - ex;
    sh = sh > 120 ? 120 : (sh < -120 ? -120 : sh);
    sc = ldexpf(1.0f, sh);
    rs = ldexpf(1.0f, -sh);
}

// ---- fused layer0: z = relu(xagg@wp1 + (deg+1)*bpW1 + b1_0); writes 4 h-slots ----
__global__ __launch_bounds__(256) void fused_l0_k(
    const float* __restrict__ x, const int* __restrict__ rp, const int* __restrict__ csr,
    const float* __restrict__ wp1, const float* __restrict__ b1_0,
    f16* __restrict__ h00, f16* __restrict__ h01,   // col0: half0, half1
    f16* __restrict__ h10, f16* __restrict__ h11,   // col1: half0, half1
    float* __restrict__ rs_out, int nreal, int half) {
    __shared__ float w[7 * HID];
    for (int idx = threadIdx.x; idx < 7 * HID; idx += 256)
        w[idx] = (idx < 6 * HID) ? wp1[idx] : b1_0[idx - 6 * HID];
    __syncthreads();
    int node = blockIdx.x * 4 + (threadIdx.x >> 6);
    int lane = threadIdx.x & 63;
    int cblk = lane >> 5, ll = lane & 31;
    f16* base;
    int rloc;
    if (node < half) { base = cblk ? h10 : h00; rloc = node; }
    else             { base = cblk ? h11 : h01; rloc = node - half; }
    f16* orow = base + (size_t)rloc * CB + ll * 12;
    if (node >= nreal) {
        #pragma unroll
        for (int t = 0; t < 12; ++t) orow[t] = (f16)0.0f;
        if (lane == 0) rs_out[node] = 1.0f;
        return;
    }
    int e0 = rp[node], e1 = rp[node + 1];
    float xa[FIN];
    #pragma unroll
    for (int k = 0; k < FIN; ++k) xa[k] = x[(size_t)node * FIN + k];
    for (int e = e0; e < e1; ++e) {
        int j = csr[e];
        #pragma unroll
        for (int k = 0; k < FIN; ++k) xa[k] += x[(size_t)j * FIN + k];
    }
    float dp1 = (float)(e1 - e0 + 1);
    float a[12];
    #pragma unroll
    for (int t = 0; t < 12; ++t) {
        int c = lane * 12 + t;
        float v = w[5 * HID + c] * dp1 + w[6 * HID + c];
        #pragma unroll
        for (int k = 0; k < FIN; ++k) v += xa[k] * w[k * HID + c];
        a[t] = fmaxf(v, 0.0f);
    }
    float amax = 0.0f;
    #pragma unroll
    for (int t = 0; t < 12; ++t) amax = fmaxf(amax, fabsf(a[t]));
    #pragma unroll
    for (int off = 32; off; off >>= 1) amax = fmaxf(amax, __shfl_xor(amax, off));
    float sc, rs;
    row_scale(amax, sc, rs);
    if (lane == 0) rs_out[node] = rs;
    #pragma unroll
    for (int t = 0; t < 12; ++t) orow[t] = (f16)(a[t] * sc);
}

// ---- aggscale: fresh per-row output scale from recorded per-row true amax ----
__global__ void aggscale_k(const float* __restrict__ amaxR, const int* __restrict__ rp,
                           const int* __restrict__ csr, float* __restrict__ rsOut,
                           int nreal, int npad) {
    int i = blockIdx.x * 256 + threadIdx.x;
    if (i >= npad) return;
    if (i >= nreal) { rsOut[i] = 1.0f; return; }
    float M = amaxR[i];
    for (int e = rp[i]; e < rp[i + 1]; ++e) M = fmaxf(M, amaxR[csr[e]]);
    float r = 1.0f;
    if (M > 0.0f) {
        int ex; frexpf(M, &ex);
        int sh = ex - 9;                      // M / 2^sh in [256,512)
        sh = sh > 120 ? 120 : (sh < -120 ? -120 : sh);
        r = ldexpf(1.0f, sh);
    }
    rsOut[i] = r;
}

// ---- aggcol: one column block (2 row-half slots in, 2 out) ----
__global__ __launch_bounds__(256) void aggcol_k(
    const f16* __restrict__ s0, const f16* __restrict__ s1,
    f16* __restrict__ d0, f16* __restrict__ d1,
    const float* __restrict__ rsIn, float inShift,
    const float* __restrict__ rsOut,
    const int* __restrict__ rp, const int* __restrict__ csr, int nreal, int half) {
    int node = blockIdx.x * 8 + (threadIdx.x >> 5);
    int l = threadIdx.x & 31;
    f16* orow = (node < half ? d0 + (size_t)node * CB : d1 + (size_t)(node - half) * CB) + l * 12;
    if (node >= nreal) {
        #pragma unroll
        for (int t = 0; t < 12; ++t) orow[t] = (f16)0.0f;
        return;
    }
    float invOut = 1.0f / rsOut[node];
    float a[12];
    {
        float f = rsIn[node] * inShift * invOut;
        const f16* srow = (node < half ? s0 + (size_t)node * CB : s1 + (size_t)(node - half) * CB);
        const f16x4* p = (const f16x4*)(srow + l * 12);
        f16x4 v0 = p[0], v1 = p[1], v2 = p[2];
        #pragma unroll
        for (int t = 0; t < 4; ++t) {
            a[t] = (float)v0[t] * f; a[4 + t] = (float)v1[t] * f; a[8 + t] = (float)v2[t] * f;
        }
    }
    int e0 = rp[node], e1 = rp[node + 1];
    for (int e = e0; e < e1; ++e) {
        int j = csr[e];
        float f = rsIn[j] * inShift * invOut;
        const f16* srow = (j < half ? s0 + (size_t)j * CB : s1 + (size_t)(j - half) * CB);
        const f16x4* p = (const f16x4*)(srow + l * 12);
        f16x4 v0 = p[0], v1 = p[1], v2 = p[2];
        #pragma unroll
        for (int t = 0; t < 4; ++t) {
            a[t] += (float)v0[t] * f; a[4 + t] += (float)v1[t] * f; a[8 + t] += (float)v2[t] * f;
        }
    }
    f16x4 o0, o1, o2;
    #pragma unroll
    for (int t = 0; t < 4; ++t) {
        o0[t] = (f16)a[t]; o1[t] = (f16)a[4 + t]; o2[t] = (f16)a[8 + t];
    }
    f16x4* op = (f16x4*)orow;
    op[0] = o0; op[1] = o1; op[2] = o2;
}

// ---- m97-structure GEMM over one row-half segment: C = relu(A@W + b), out-of-place.
// A from 2 col-block slots [half][384]; W = wt [n][k] fp16*64; C to 2 col-block slots.
// 128x128 tile, BK=64, 4 waves (2x2), global_load_lds 16B, mfma 16x16x32 f16.
// Output stored scale: 1/(rs[row]*shiftIn*8); optional true-amax record via atomicMax.
__global__ __launch_bounds__(256) void gemm_seg_k(
    const f16* __restrict__ a0, const f16* __restrict__ a1,
    f16* __restrict__ c0, f16* __restrict__ c1,
    const float* __restrict__ rs, int rsOff, float shiftIn,
    const f16* __restrict__ wt, const float* __restrict__ bias,
    float* __restrict__ amaxR, int recAmax) {
    __shared__ f16 As[128 * 64];
    __shared__ f16 Bs[128 * 64];
    const int tid = threadIdx.x;
    const int lane = tid & 63;
    const int wid = tid >> 6;
    const int m0 = blockIdx.x * 128;   // M fastest: consecutive blocks share B n-panel (L2)
    const int n0 = blockIdx.y * 128;
    const int wr = (wid >> 1) * 64;
    const int wc = (wid & 1) * 64;

    f32x4 acc[4][4];
    #pragma unroll
    for (int m = 0; m < 4; ++m)
        #pragma unroll
        for (int n = 0; n < 4; ++n) acc[m][n] = (f32x4){0.f, 0.f, 0.f, 0.f};

    const int lrow = lane >> 3;       // 0..7 within 8-row chunk
    const int lcol = (lane & 7) * 8;  // 0..56

    for (int kt = 0; kt < 12; ++kt) {
        const f16* abase = (kt < 6) ? a0 : a1;
        const int kb = (kt < 6 ? kt : kt - 6) * 64;
        const int kw = kt * 64;
        #pragma unroll
        for (int i = 0; i < 4; ++i) {
            int chunk = i * 4 + wid;          // 0..15, wave-uniform
            int row = chunk * 8 + lrow;
            const f16* ga = abase + (size_t)(m0 + row) * CB + kb + lcol;
            __builtin_amdgcn_global_load_lds(
                (const __attribute__((address_space(1))) void*)ga,
                (__attribute__((address_space(3))) void*)(As + chunk * 512), 16, 0, 0);
            const f16* gb = wt + (size_t)(n0 + row) * HID + kw + lcol;
            __builtin_amdgcn_global_load_lds(
                (const __attribute__((address_space(1))) void*)gb,
                (__attribute__((address_space(3))) void*)(Bs + chunk * 512), 16, 0, 0);
        }
        __syncthreads();
        #pragma unroll
        for (int kk = 0; kk < 2; ++kk) {
            const int kf = kk * 32 + (lane >> 4) * 8;
            f16x8 af[4], bfr[4];
            #pragma unroll
            for (int m = 0; m < 4; ++m)
                af[m] = *(const f16x8*)(As + (wr + m * 16 + (lane & 15)) * 64 + kf);
            #pragma unroll
            for (int n = 0; n < 4; ++n)
                bfr[n] = *(const f16x8*)(Bs + (wc + n * 16 + (lane & 15)) * 64 + kf);
            #pragma unroll
            for (int m = 0; m < 4; ++m)
                #pragma unroll
                for (int n = 0; n < 4; ++n)
                    acc[m][n] = __builtin_amdgcn_mfma_f32_16x16x32_f16(af[m], bfr[n], acc[m][n], 0, 0, 0);
        }
        __syncthreads();
    }

    const int l15 = lane & 15, l4 = lane >> 4;
    const int cbase = n0 + wc + l15;
    const int rbase = m0 + wr + (l4 << 2);
    float rvv[16], rinvv[16], am[16];
    #pragma unroll
    for (int m = 0; m < 4; ++m)
        #pragma unroll
        for (int r = 0; r < 4; ++r) {
            int row = rbase + m * 16 + r;
            float rv = rs[rsOff + row] * shiftIn * 8.0f;
            rvv[m * 4 + r] = rv;
            rinvv[m * 4 + r] = 1.0f / rv;
            am[m * 4 + r] = 0.0f;
        }
    #pragma unroll
    for (int n = 0; n < 4; ++n) {
        const int col = cbase + n * 16;
        const float bcol = bias[col];
        #pragma unroll
        for (int m = 0; m < 4; ++m) {
            #pragma unroll
            for (int r = 0; r < 4; ++r) {
                const int row = rbase + m * 16 + r;
                float v = acc[m][n][r] * (1.0f / 512.0f) + bcol * rinvv[m * 4 + r];
                v = fmaxf(v, 0.0f);
                am[m * 4 + r] = fmaxf(am[m * 4 + r], v);
                f16 h = (f16)v;
                if (col < CB) c0[(size_t)row * CB + col] = h;
                else          c1[(size_t)row * CB + col - CB] = h;
            }
        }
    }
    if (recAmax) {
        #pragma unroll
        for (int i = 0; i < 16; ++i) {
            float a = am[i];
            a = fmaxf(a, __shfl_xor(a, 1));
            a = fmaxf(a, __shfl_xor(a, 2));
            a = fmaxf(a, __shfl_xor(a, 4));
            a = fmaxf(a, __shfl_xor(a, 8));
            if (l15 == 0) {
                int row = rbase + (i >> 2) * 16 + (i & 3);
                atomicMax((unsigned int*)&amaxR[rsOff + row], __float_as_uint(a * rvv[i]));
            }
        }
    }
}

// ---- pooling: deterministic per-graph serial sum over 4 h-slots ----
__global__ __launch_bounds__(256) void pool_k(
    const f16* __restrict__ h00, const f16* __restrict__ h01,
    const f16* __restrict__ h10, const f16* __restrict__ h11,
    const float* __restrict__ rs, float shift,
    const int* __restrict__ goff, float* __restrict__ pooled, int half) {
    int g = blockIdx.x, c = blockIdx.y;
    int t = threadIdx.x;
    int col = c * 256 + t;
    int cb = col >= CB;
    int cc = cb ? col - CB : col;
    int i0 = goff[g], i1 = goff[g + 1];
    float a = 0.0f;
    for (int i = i0; i < i1; ++i) {
        const f16* base = (i < half) ? (cb ? h10 : h00) : (cb ? h11 : h01);
        int r = (i < half) ? i : i - half;
        a += (float)base[(size_t)r * CB + cc] * rs[i];
    }
    pooled[g * HID + col] = a * shift;
}

__global__ __launch_bounds__(512) void final_mm_k(const float* __restrict__ pooled,
                                                  const int* __restrict__ goff,
                                                  const float* __restrict__ Wf,
                                                  const float* __restrict__ bf,
                                                  float* __restrict__ out) {
    __shared__ float ps[HID];
    int g = blockIdx.x;
    int t = threadIdx.x;
    float inv = 1.0f / fmaxf((float)(goff[g + 1] - goff[g]), 1.0f);
    for (int k = t; k < HID; k += 512) ps[k] = pooled[g * HID + k] * inv;
    __syncthreads();
    float acc = bf[t];
    for (int k = 0; k < HID; ++k) acc += ps[k] * Wf[(size_t)k * EMB + t];
    out[(size_t)g * EMB + t] = acc;
}

__global__ void sentinel_k(float* __restrict__ out, int n, float v) {
    int i = blockIdx.x * 256 + threadIdx.x;
    if (i < n) out[i] = v;
}

// ---------------- launch ----------------
extern "C" void kernel_launch(void* const* d_in, const int* in_sizes, int n_in,
                              void* d_out, int out_size, void* d_ws, size_t ws_size,
                              hipStream_t stream) {
    const float* x    = (const float*)d_in[0];
    const int*   ei   = (const int*)d_in[1];
    const int*   batch= (const int*)d_in[2];
    const float* Wp   = (const float*)d_in[3];
    const float* bp   = (const float*)d_in[4];
    const float* W1   = (const float*)d_in[5];
    const float* b1   = (const float*)d_in[6];
    const float* W2   = (const float*)d_in[7];
    const float* b2   = (const float*)d_in[8];
    const float* Wf   = (const float*)d_in[9];
    const float* bf   = (const float*)d_in[10];
    float* out = (float*)d_out;

    const int nreal = in_sizes[0] / FIN;              // 100000
    const int E     = in_sizes[1] / 2;                // 200000
    const int npad  = ((nreal + 255) / 256) * 256;    // 100352
    const int half  = npad / 2;                       // 50176 (392 tiles of 128)
    const size_t slotsz = (size_t)half * CB;          // f16 elements per slot

    char* p = (char*)d_ws;
    auto alloc = [&](size_t bytes) -> char* {
        char* r = p; p += (bytes + 511) & ~(size_t)511; return r;
    };
    f16* slot[6];
    for (int i = 0; i < 6; ++i) slot[i] = (f16*)alloc(slotsz * sizeof(f16));
    f16*   wt   = (f16*)  alloc((size_t)2 * HID * HID * sizeof(f16));
    float* rsA  = (float*)alloc((size_t)npad * sizeof(float));
    float* rsB  = (float*)alloc((size_t)npad * sizeof(float));
    float* amaxR= (float*)alloc((size_t)npad * sizeof(float));
    int*   rp   = (int*)  alloc((size_t)(npad + 1) * sizeof(int));
    int*   csr  = (int*)  alloc((size_t)E * sizeof(int));
    float* wp1  = (float*)alloc((size_t)6 * HID * sizeof(float));
    int*   goff = (int*)  alloc((size_t)(NG + 1) * sizeof(int));
    float* pooled = (float*)alloc((size_t)NG * HID * sizeof(float));
    char*  zstart = p;
    int*   deg  = (int*)  alloc((size_t)npad * sizeof(int));
    int*   cur  = (int*)  alloc((size_t)npad * sizeof(int));
    int*   gcnt = (int*)  alloc((size_t)NG * sizeof(int));
    size_t zbytes = (size_t)(p - zstart);
    size_t need  = (size_t)(p - (char*)d_ws);

    if (need > ws_size) {
        sentinel_k<<<(out_size + 255) / 256, 256, 0, stream>>>(out, out_size, (float)(ws_size >> 20));
        return;
    }

    hipMemsetAsync(zstart, 0, zbytes, stream);

    count_deg_k  <<<(E + 255) / 256, 256, 0, stream>>>(ei, deg, E);
    count_nodes_k<<<(nreal + 255) / 256, 256, 0, stream>>>(batch, gcnt, nreal);
    scan_rowptr_k<<<1, 1024, 0, stream>>>(deg, rp, cur, nreal);
    scatter_k    <<<(E + 255) / 256, 256, 0, stream>>>(ei, cur, csr, E);
    sort_csr_k   <<<(nreal + 255) / 256, 256, 0, stream>>>(rp, csr, nreal);
    gscan_k      <<<1, 64, 0, stream>>>(gcnt, goff);

    make_wp1_k<<<(HID + 255) / 256, 256, 0, stream>>>(Wp, bp, W1, wp1);

    // h slots: h00,h01 = col0 halves; h10,h11 = col1 halves; f0,f1 spare
    f16 *h00 = slot[0], *h01 = slot[1], *h10 = slot[2], *h11 = slot[3];
    f16 *f0 = slot[4], *f1 = slot[5];

    fused_l0_k<<<npad / 4, 256, 0, stream>>>(x, rp, csr, wp1, b1, h00, h01, h10, h11, rsA, nreal, half);

    const dim3 ggrid(half / 128, HID / 128);   // (392, 6)

    // layer 0 second matmul (W2[0]): row-half rotation, records amax
    convert_layer_k<<<dim3(HID / 64, HID / 64, 2), 256, 0, stream>>>(W1, W2, wt);
    hipMemsetAsync(amaxR, 0, (size_t)npad * sizeof(float), stream);
    gemm_seg_k<<<ggrid, 256, 0, stream>>>(h00, h10, f0, f1, rsA, 0, 1.0f,
                                          wt + (size_t)HID * HID, b2, amaxR, 1);
    gemm_seg_k<<<ggrid, 256, 0, stream>>>(h01, h11, h00, h10, rsA, half, 1.0f,
                                          wt + (size_t)HID * HID, b2, amaxR, 1);
    { f16 *n00 = f0, *n10 = f1, *n01 = h00, *n11 = h10, *nf0 = h01, *nf1 = h11;
      h00 = n00; h10 = n10; h01 = n01; h11 = n11; f0 = nf0; f1 = nf1; }

    float* rcur = rsA;
    float  shift = 8.0f;   // stored h = true / (rcur * shift)

    for (int l = 1; l < NL; ++l) {
        convert_layer_k<<<dim3(HID / 64, HID / 64, 2), 256, 0, stream>>>(
            W1 + (size_t)l * HID * HID, W2 + (size_t)l * HID * HID, wt);
        float* rnew = (rcur == rsA) ? rsB : rsA;
        aggscale_k<<<(npad + 255) / 256, 256, 0, stream>>>(amaxR, rp, csr, rnew, nreal, npad);
        // agg col0: (h00,h01) -> (f0,f1); agg col1: (h10,h11) -> (h00,h01)
        aggcol_k<<<npad / 8, 256, 0, stream>>>(h00, h01, f0, f1, rcur, shift, rnew, rp, csr, nreal, half);
        aggcol_k<<<npad / 8, 256, 0, stream>>>(h10, h11, h00, h01, rcur, shift, rnew, rp, csr, nreal, half);
        f16 *g00 = f0, *g01 = f1, *g10 = h00, *g11 = h01, *x0 = h10, *x1 = h11;
        // GEMM1 (W1_l): half0 in(g00,g10)->out(x0,x1); half1 in(g01,g11)->out(g00,g10)
        gemm_seg_k<<<ggrid, 256, 0, stream>>>(g00, g10, x0, x1, rnew, 0, 1.0f,
                                              wt, b1 + (size_t)l * HID, amaxR, 0);
        gemm_seg_k<<<ggrid, 256, 0, stream>>>(g01, g11, g00, g10, rnew, half, 1.0f,
                                              wt, b1 + (size_t)l * HID, amaxR, 0);
        f16 *z00 = x0, *z10 = x1, *z01 = g00, *z11 = g10;   // free: g01,g11
        // GEMM2 (W2_l): records amax
        hipMemsetAsync(amaxR, 0, (size_t)npad * sizeof(float), stream);
        gemm_seg_k<<<ggrid, 256, 0, stream>>>(z00, z10, g01, g11, rnew, 0, 8.0f,
                                              wt + (size_t)HID * HID, b2 + (size_t)l * HID, amaxR, 1);
        gemm_seg_k<<<ggrid, 256, 0, stream>>>(z01, z11, z00, z10, rnew, half, 8.0f,
                                              wt + (size_t)HID * HID, b2 + (size_t)l * HID, amaxR, 1);
        h00 = g01; h10 = g11; h01 = z00; h11 = z10; f0 = g00; f1 = g10;
        rcur = rnew;
        shift = 64.0f;
    }

    pool_k<<<dim3(NG, HID / 256), 256, 0, stream>>>(h00, h01, h10, h11, rcur, shift, goff, pooled, half);
    final_mm_k<<<NG, 512, 0, stream>>>(pooled, goff, Wf, bf, out);
}

// Round 7
// 9347.581 us; speedup vs baseline: 2.0657x; 1.1105x over previous
//
#include <hip/hip_runtime.h>

#define HID 768
#define EMB 512
#define NG  64
#define FIN 5
#define NL  16
#define CB  384   // column block width (HID/2)

typedef _Float16 f16;
typedef f16   f16x4 __attribute__((ext_vector_type(4)));
typedef f16   f16x8 __attribute__((ext_vector_type(8)));
typedef float f32x4 __attribute__((ext_vector_type(4)));

// ---------------- CSR build ----------------
__global__ void count_deg_k(const int* __restrict__ ei, int* __restrict__ deg, int E) {
    int e = blockIdx.x * 256 + threadIdx.x;
    if (e < E) atomicAdd(&deg[ei[E + e]], 1);
}

// batch is sorted: goff[g] = lower_bound(batch, g); no atomics (count_nodes_k was 500us of
// same-cacheline atomic contention).
__global__ void goff_k(const int* __restrict__ batch, int* __restrict__ goff, int n) {
    int g = threadIdx.x;
    if (g > NG) return;
    if (g == NG) { goff[NG] = n; return; }
    int lo = 0, hi = n;
    while (lo < hi) { int mid = (lo + hi) >> 1; if (batch[mid] < g) lo = mid + 1; else hi = mid; }
    goff[g] = lo;
}

__global__ void scan_rowptr_k(const int* __restrict__ deg, int* __restrict__ rp,
                              int* __restrict__ cur, int n) {
    __shared__ int wsum[16];
    __shared__ int carry;
    int t = threadIdx.x, lane = t & 63, w = t >> 6;
    if (t == 0) carry = 0;
    __syncthreads();
    for (int base = 0; base < n; base += 4096) {
        int v[4]; int s = 0;
        #pragma unroll
        for (int q = 0; q < 4; ++q) { int i = base + t * 4 + q; v[q] = (i < n) ? deg[i] : 0; s += v[q]; }
        int tot = s;
        int sc = tot;
        #pragma unroll
        for (int off = 1; off < 64; off <<= 1) { int u = __shfl_up(sc, off); if (lane >= off) sc += u; }
        if (lane == 63) wsum[w] = sc;
        __syncthreads();
        if (t < 16) {
            int xw = wsum[t];
            #pragma unroll
            for (int off = 1; off < 16; off <<= 1) { int u = __shfl_up(xw, off); if (t >= off) xw += u; }
            wsum[t] = xw;
        }
        __syncthreads();
        int woff = (w > 0) ? wsum[w - 1] : 0;
        int excl = carry + woff + sc - tot;
        #pragma unroll
        for (int q = 0; q < 4; ++q) { int i = base + t * 4 + q; if (i < n) { rp[i] = excl; cur[i] = excl; } excl += v[q]; }
        __syncthreads();
        if (t == 0) carry += wsum[15];
        __syncthreads();
    }
    if (t == 0) rp[n] = carry;
}

__global__ void scatter_k(const int* __restrict__ ei, int* __restrict__ cur,
                          int* __restrict__ csr, int E) {
    int e = blockIdx.x * 256 + threadIdx.x;
    if (e < E) { int d = ei[E + e]; int pos = atomicAdd(&cur[d], 1); csr[pos] = ei[e]; }
}

// canonicalize neighbor order (atomic scatter order varies call-to-call)
__global__ void sort_csr_k(const int* __restrict__ rp, int* __restrict__ csr, int n) {
    int i = blockIdx.x * 256 + threadIdx.x;
    if (i >= n) return;
    int e0 = rp[i], e1 = rp[i + 1];
    for (int a = e0 + 1; a < e1; ++a) {
        int v = csr[a];
        int b = a - 1;
        while (b >= e0 && csr[b] > v) { csr[b + 1] = csr[b]; --b; }
        csr[b + 1] = v;
    }
}

// ---- per-layer weight convert: W[k][n] fp32 -> wt[z][n][k] fp16 * 64 ----
__global__ void convert_layer_k(const float* __restrict__ Wa, const float* __restrict__ Wb,
                                f16* __restrict__ wt) {
    __shared__ float tile[64][65];
    const float* src = blockIdx.z ? Wb : Wa;
    f16* dst = wt + (size_t)blockIdx.z * HID * HID;
    int k0 = blockIdx.x * 64, n0 = blockIdx.y * 64;
    int t = threadIdx.x;
    #pragma unroll 4
    for (int i = 0; i < 16; ++i) {
        int r = (t >> 6) + i * 4;
        tile[r][t & 63] = src[(size_t)(k0 + r) * HID + n0 + (t & 63)];
    }
    __syncthreads();
    #pragma unroll 4
    for (int i = 0; i < 16; ++i) {
        int r = (t >> 6) + i * 4;
        dst[(size_t)(n0 + r) * HID + k0 + (t & 63)] = (f16)(tile[t & 63][r] * 64.0f);
    }
}

// ---- layer-0 folding ----
__global__ void make_wp1_k(const float* __restrict__ Wp, const float* __restrict__ bp,
                           const float* __restrict__ W1_0, float* __restrict__ wp1) {
    int nn = blockIdx.x * 256 + threadIdx.x;
    if (nn >= HID) return;
    float acc[6] = {0, 0, 0, 0, 0, 0};
    for (int j = 0; j < HID; ++j) {
        float wj = W1_0[(size_t)j * HID + nn];
        #pragma unroll
        for (int k = 0; k < FIN; ++k) acc[k] += Wp[k * HID + j] * wj;
        acc[5] += bp[j] * wj;
    }
    #pragma unroll
    for (int k = 0; k < 6; ++k) wp1[k * HID + nn] = acc[k];
}

__device__ __forceinline__ void row_scale(float amax, float& sc, float& rs) {
    int ex = 10;
    if (amax > 0.0f) frexpf(amax, &ex);
    int sh = 10 - ex;
    sh = sh > 120 ? 120 : (sh < -120 ? -120 : sh);
    sc = ldexpf(1.0f, sh);
    rs = ldexpf(1.0f, -sh);
}

// ---- fused layer0: z = relu(xagg@wp1 + (deg+1)*bpW1 + b1_0); writes 4 h-slots ----
__global__ __launch_bounds__(256) void fused_l0_k(
    const float* __restrict__ x, const int* __restrict__ rp, const int* __restrict__ csr,
    const float* __restrict__ wp1, const float* __restrict__ b1_0,
    f16* __restrict__ h00, f16* __restrict__ h01,   // col0: half0, half1
    f16* __restrict__ h10, f16* __restrict__ h11,   // col1: half0, half1
    float* __restrict__ rs_out, int nreal, int half) {
    __shared__ float w[7 * HID];
    for (int idx = threadIdx.x; idx < 7 * HID; idx += 256)
        w[idx] = (idx < 6 * HID) ? wp1[idx] : b1_0[idx - 6 * HID];
    __syncthreads();
    int node = blockIdx.x * 4 + (threadIdx.x >> 6);
    int lane = threadIdx.x & 63;
    int cblk = lane >> 5, ll = lane & 31;
    f16* base;
    int rloc;
    if (node < half) { base = cblk ? h10 : h00; rloc = node; }
    else             { base = cblk ? h11 : h01; rloc = node - half; }
    f16* orow = base + (size_t)rloc * CB + ll * 12;
    if (node >= nreal) {
        #pragma unroll
        for (int t = 0; t < 12; ++t) orow[t] = (f16)0.0f;
        if (lane == 0) rs_out[node] = 1.0f;
        return;
    }
    int e0 = rp[node], e1 = rp[node + 1];
    float xa[FIN];
    #pragma unroll
    for (int k = 0; k < FIN; ++k) xa[k] = x[(size_t)node * FIN + k];
    for (int e = e0; e < e1; ++e) {
        int j = csr[e];
        #pragma unroll
        for (int k = 0; k < FIN; ++k) xa[k] += x[(size_t)j * FIN + k];
    }
    float dp1 = (float)(e1 - e0 + 1);
    float a[12];
    #pragma unroll
    for (int t = 0; t < 12; ++t) {
        int c = lane * 12 + t;
        float v = w[5 * HID + c] * dp1 + w[6 * HID + c];
        #pragma unroll
        for (int k = 0; k < FIN; ++k) v += xa[k] * w[k * HID + c];
        a[t] = fmaxf(v, 0.0f);
    }
    float amax = 0.0f;
    #pragma unroll
    for (int t = 0; t < 12; ++t) amax = fmaxf(amax, fabsf(a[t]));
    #pragma unroll
    for (int off = 32; off; off >>= 1) amax = fmaxf(amax, __shfl_xor(amax, off));
    float sc, rs;
    row_scale(amax, sc, rs);
    if (lane == 0) rs_out[node] = rs;
    #pragma unroll
    for (int t = 0; t < 12; ++t) orow[t] = (f16)(a[t] * sc);
}

// ---- aggscale: fresh per-row output scale from recorded per-row true amax ----
__global__ void aggscale_k(const float* __restrict__ amaxR, const int* __restrict__ rp,
                           const int* __restrict__ csr, float* __restrict__ rsOut,
                           int nreal, int npad) {
    int i = blockIdx.x * 256 + threadIdx.x;
    if (i >= npad) return;
    if (i >= nreal) { rsOut[i] = 1.0f; return; }
    float M = amaxR[i];
    for (int e = rp[i]; e < rp[i + 1]; ++e) M = fmaxf(M, amaxR[csr[e]]);
    float r = 1.0f;
    if (M > 0.0f) {
        int ex; frexpf(M, &ex);
        int sh = ex - 9;                      // M / 2^sh in [256,512)
        sh = sh > 120 ? 120 : (sh < -120 ? -120 : sh);
        r = ldexpf(1.0f, sh);
    }
    rsOut[i] = r;
}

// ---- aggcol: one column block (2 row-half slots in, 2 out) ----
__global__ __launch_bounds__(256) void aggcol_k(
    const f16* __restrict__ s0, const f16* __restrict__ s1,
    f16* __restrict__ d0, f16* __restrict__ d1,
    const float* __restrict__ rsIn, float inShift,
    const float* __restrict__ rsOut,
    const int* __restrict__ rp, const int* __restrict__ csr, int nreal, int half) {
    int node = blockIdx.x * 8 + (threadIdx.x >> 5);
    int l = threadIdx.x & 31;
    f16* orow = (node < half ? d0 + (size_t)node * CB : d1 + (size_t)(node - half) * CB) + l * 12;
    if (node >= nreal) {
        #pragma unroll
        for (int t = 0; t < 12; ++t) orow[t] = (f16)0.0f;
        return;
    }
    float invOut = 1.0f / rsOut[node];
    float a[12];
    {
        float f = rsIn[node] * inShift * invOut;
        const f16* srow = (node < half ? s0 + (size_t)node * CB : s1 + (size_t)(node - half) * CB);
        const f16x4* p = (const f16x4*)(srow + l * 12);
        f16x4 v0 = p[0], v1 = p[1], v2 = p[2];
        #pragma unroll
        for (int t = 0; t < 4; ++t) {
            a[t] = (float)v0[t] * f; a[4 + t] = (float)v1[t] * f; a[8 + t] = (float)v2[t] * f;
        }
    }
    int e0 = rp[node], e1 = rp[node + 1];
    for (int e = e0; e < e1; ++e) {
        int j = csr[e];
        float f = rsIn[j] * inShift * invOut;
        const f16* srow = (j < half ? s0 + (size_t)j * CB : s1 + (size_t)(j - half) * CB);
        const f16x4* p = (const f16x4*)(srow + l * 12);
        f16x4 v0 = p[0], v1 = p[1], v2 = p[2];
        #pragma unroll
        for (int t = 0; t < 4; ++t) {
            a[t] += (float)v0[t] * f; a[4 + t] += (float)v1[t] * f; a[8 + t] += (float)v2[t] * f;
        }
    }
    f16x4 o0, o1, o2;
    #pragma unroll
    for (int t = 0; t < 4; ++t) {
        o0[t] = (f16)a[t]; o1[t] = (f16)a[4 + t]; o2[t] = (f16)a[8 + t];
    }
    f16x4* op = (f16x4*)orow;
    op[0] = o0; op[1] = o1; op[2] = o2;
}

// ---- m97-structure GEMM over one row-half segment, XCD-swizzled flat grid.
// Each XCD owns ~49 consecutive m-tiles x all 6 n-panels: A-tile L2 reuse (6x),
// whole B (1.18 MB) L2-resident. 128x128 tile, BK=64, global_load_lds 16B.
__global__ __launch_bounds__(256) void gemm_seg_k(
    const f16* __restrict__ a0, const f16* __restrict__ a1,
    f16* __restrict__ c0, f16* __restrict__ c1,
    const float* __restrict__ rs, int rsOff, float shiftIn,
    const f16* __restrict__ wt, const float* __restrict__ bias,
    float* __restrict__ amaxR, int recAmax) {
    __shared__ f16 As[128 * 64];
    __shared__ f16 Bs[128 * 64];
    const int tid = threadIdx.x;
    const int lane = tid & 63;
    const int wid = tid >> 6;

    // bijective XCD swizzle (ERRATA #11 form), then n-fastest within chunk
    const int nwg = gridDim.x;
    const int q = nwg >> 3, r = nwg & 7;
    const int xcd = blockIdx.x & 7, loc = blockIdx.x >> 3;
    const int id2 = (xcd < r ? xcd * (q + 1) : r * (q + 1) + (xcd - r) * q) + loc;
    const int m0 = (id2 / 6) * 128;
    const int n0 = (id2 % 6) * 128;

    const int wr = (wid >> 1) * 64;
    const int wc = (wid & 1) * 64;

    f32x4 acc[4][4];
    #pragma unroll
    for (int m = 0; m < 4; ++m)
        #pragma unroll
        for (int n = 0; n < 4; ++n) acc[m][n] = (f32x4){0.f, 0.f, 0.f, 0.f};

    const int lrow = lane >> 3;       // 0..7 within 8-row chunk
    const int lcol = (lane & 7) * 8;  // 0..56

    for (int kt = 0; kt < 12; ++kt) {
        const f16* abase = (kt < 6) ? a0 : a1;
        const int kb = (kt < 6 ? kt : kt - 6) * 64;
        const int kw = kt * 64;
        #pragma unroll
        for (int i = 0; i < 4; ++i) {
            int chunk = i * 4 + wid;          // 0..15, wave-uniform
            int row = chunk * 8 + lrow;
            const f16* ga = abase + (size_t)(m0 + row) * CB + kb + lcol;
            __builtin_amdgcn_global_load_lds(
                (const __attribute__((address_space(1))) void*)ga,
                (__attribute__((address_space(3))) void*)(As + chunk * 512), 16, 0, 0);
            const f16* gb = wt + (size_t)(n0 + row) * HID + kw + lcol;
            __builtin_amdgcn_global_load_lds(
                (const __attribute__((address_space(1))) void*)gb,
                (__attribute__((address_space(3))) void*)(Bs + chunk * 512), 16, 0, 0);
        }
        __syncthreads();
        #pragma unroll
        for (int kk = 0; kk < 2; ++kk) {
            const int kf = kk * 32 + (lane >> 4) * 8;
            f16x8 af[4], bfr[4];
            #pragma unroll
            for (int m = 0; m < 4; ++m)
                af[m] = *(const f16x8*)(As + (wr + m * 16 + (lane & 15)) * 64 + kf);
            #pragma unroll
            for (int n = 0; n < 4; ++n)
                bfr[n] = *(const f16x8*)(Bs + (wc + n * 16 + (lane & 15)) * 64 + kf);
            #pragma unroll
            for (int m = 0; m < 4; ++m)
                #pragma unroll
                for (int n = 0; n < 4; ++n)
                    acc[m][n] = __builtin_amdgcn_mfma_f32_16x16x32_f16(af[m], bfr[n], acc[m][n], 0, 0, 0);
        }
        __syncthreads();
    }

    const int l15 = lane & 15, l4 = lane >> 4;
    const int cbase = n0 + wc + l15;
    const int rbase = m0 + wr + (l4 << 2);
    float rvv[16], rinvv[16], am[16];
    #pragma unroll
    for (int m = 0; m < 4; ++m)
        #pragma unroll
        for (int r2 = 0; r2 < 4; ++r2) {
            int row = rbase + m * 16 + r2;
            float rv = rs[rsOff + row] * shiftIn * 8.0f;
            rvv[m * 4 + r2] = rv;
            rinvv[m * 4 + r2] = 1.0f / rv;
            am[m * 4 + r2] = 0.0f;
        }
    #pragma unroll
    for (int n = 0; n < 4; ++n) {
        const int col = cbase + n * 16;
        const float bcol = bias[col];
        #pragma unroll
        for (int m = 0; m < 4; ++m) {
            #pragma unroll
            for (int r2 = 0; r2 < 4; ++r2) {
                const int row = rbase + m * 16 + r2;
                float v = acc[m][n][r2] * (1.0f / 512.0f) + bcol * rinvv[m * 4 + r2];
                v = fmaxf(v, 0.0f);
                am[m * 4 + r2] = fmaxf(am[m * 4 + r2], v);
                f16 h = (f16)v;
                if (col < CB) c0[(size_t)row * CB + col] = h;
                else          c1[(size_t)row * CB + col - CB] = h;
            }
        }
    }
    if (recAmax) {
        #pragma unroll
        for (int i = 0; i < 16; ++i) {
            float a = am[i];
            a = fmaxf(a, __shfl_xor(a, 1));
            a = fmaxf(a, __shfl_xor(a, 2));
            a = fmaxf(a, __shfl_xor(a, 4));
            a = fmaxf(a, __shfl_xor(a, 8));
            if (l15 == 0) {
                int row = rbase + (i >> 2) * 16 + (i & 3);
                atomicMax((unsigned int*)&amaxR[rsOff + row], __float_as_uint(a * rvv[i]));
            }
        }
    }
}

// ---- pooling: deterministic per-graph serial sum over 4 h-slots ----
__global__ __launch_bounds__(256) void pool_k(
    const f16* __restrict__ h00, const f16* __restrict__ h01,
    const f16* __restrict__ h10, const f16* __restrict__ h11,
    const float* __restrict__ rs, float shift,
    const int* __restrict__ goff, float* __restrict__ pooled, int half) {
    int g = blockIdx.x, c = blockIdx.y;
    int t = threadIdx.x;
    int col = c * 256 + t;
    int cb = col >= CB;
    int cc = cb ? col - CB : col;
    int i0 = goff[g], i1 = goff[g + 1];
    float a = 0.0f;
    for (int i = i0; i < i1; ++i) {
        const f16* base = (i < half) ? (cb ? h10 : h00) : (cb ? h11 : h01);
        int r = (i < half) ? i : i - half;
        a += (float)base[(size_t)r * CB + cc] * rs[i];
    }
    pooled[g * HID + col] = a * shift;
}

__global__ __launch_bounds__(512) void final_mm_k(const float* __restrict__ pooled,
                                                  const int* __restrict__ goff,
                                                  const float* __restrict__ Wf,
                                                  const float* __restrict__ bf,
                                                  float* __restrict__ out) {
    __shared__ float ps[HID];
    int g = blockIdx.x;
    int t = threadIdx.x;
    float inv = 1.0f / fmaxf((float)(goff[g + 1] - goff[g]), 1.0f);
    for (int k = t; k < HID; k += 512) ps[k] = pooled[g * HID + k] * inv;
    __syncthreads();
    float acc = bf[t];
    for (int k = 0; k < HID; ++k) acc += ps[k] * Wf[(size_t)k * EMB + t];
    out[(size_t)g * EMB + t] = acc;
}

__global__ void sentinel_k(float* __restrict__ out, int n, float v) {
    int i = blockIdx.x * 256 + threadIdx.x;
    if (i < n) out[i] = v;
}

// ---------------- launch ----------------
extern "C" void kernel_launch(void* const* d_in, const int* in_sizes, int n_in,
                              void* d_out, int out_size, void* d_ws, size_t ws_size,
                              hipStream_t stream) {
    const float* x    = (const float*)d_in[0];
    const int*   ei   = (const int*)d_in[1];
    const int*   batch= (const int*)d_in[2];
    const float* Wp   = (const float*)d_in[3];
    const float* bp   = (const float*)d_in[4];
    const float* W1   = (const float*)d_in[5];
    const float* b1   = (const float*)d_in[6];
    const float* W2   = (const float*)d_in[7];
    const float* b2   = (const float*)d_in[8];
    const float* Wf   = (const float*)d_in[9];
    const float* bf   = (const float*)d_in[10];
    float* out = (float*)d_out;

    const int nreal = in_sizes[0] / FIN;              // 100000
    const int E     = in_sizes[1] / 2;                // 200000
    const int npad  = ((nreal + 255) / 256) * 256;    // 100352
    const int half  = npad / 2;                       // 50176 (392 tiles of 128)
    const size_t slotsz = (size_t)half * CB;          // f16 elements per slot

    char* p = (char*)d_ws;
    auto alloc = [&](size_t bytes) -> char* {
        char* r = p; p += (bytes + 511) & ~(size_t)511; return r;
    };
    f16* slot[6];
    for (int i = 0; i < 6; ++i) slot[i] = (f16*)alloc(slotsz * sizeof(f16));
    f16*   wt   = (f16*)  alloc((size_t)2 * HID * HID * sizeof(f16));
    float* rsA  = (float*)alloc((size_t)npad * sizeof(float));
    float* rsB  = (float*)alloc((size_t)npad * sizeof(float));
    float* amaxR= (float*)alloc((size_t)npad * sizeof(float));
    int*   rp   = (int*)  alloc((size_t)(npad + 1) * sizeof(int));
    int*   csr  = (int*)  alloc((size_t)E * sizeof(int));
    float* wp1  = (float*)alloc((size_t)6 * HID * sizeof(float));
    int*   goff = (int*)  alloc((size_t)(NG + 1) * sizeof(int));
    float* pooled = (float*)alloc((size_t)NG * HID * sizeof(float));
    char*  zstart = p;
    int*   deg  = (int*)  alloc((size_t)npad * sizeof(int));
    int*   cur  = (int*)  alloc((size_t)npad * sizeof(int));
    size_t zbytes = (size_t)(p - zstart);
    size_t need  = (size_t)(p - (char*)d_ws);

    if (need > ws_size) {
        sentinel_k<<<(out_size + 255) / 256, 256, 0, stream>>>(out, out_size, (float)(ws_size >> 20));
        return;
    }

    hipMemsetAsync(zstart, 0, zbytes, stream);

    count_deg_k  <<<(E + 255) / 256, 256, 0, stream>>>(ei, deg, E);
    goff_k       <<<1, 128, 0, stream>>>(batch, goff, nreal);
    scan_rowptr_k<<<1, 1024, 0, stream>>>(deg, rp, cur, nreal);
    scatter_k    <<<(E + 255) / 256, 256, 0, stream>>>(ei, cur, csr, E);
    sort_csr_k   <<<(nreal + 255) / 256, 256, 0, stream>>>(rp, csr, nreal);

    make_wp1_k<<<(HID + 255) / 256, 256, 0, stream>>>(Wp, bp, W1, wp1);

    // h slots: h00,h01 = col0 halves; h10,h11 = col1 halves; f0,f1 spare
    f16 *h00 = slot[0], *h01 = slot[1], *h10 = slot[2], *h11 = slot[3];
    f16 *f0 = slot[4], *f1 = slot[5];

    fused_l0_k<<<npad / 4, 256, 0, stream>>>(x, rp, csr, wp1, b1, h00, h01, h10, h11, rsA, nreal, half);

    const int nwg = (half / 128) * (HID / 128);   // 392*6 = 2352

    // layer 0 second matmul (W2[0]): row-half rotation, records amax
    convert_layer_k<<<dim3(HID / 64, HID / 64, 2), 256, 0, stream>>>(W1, W2, wt);
    hipMemsetAsync(amaxR, 0, (size_t)npad * sizeof(float), stream);
    gemm_seg_k<<<nwg, 256, 0, stream>>>(h00, h10, f0, f1, rsA, 0, 1.0f,
                                        wt + (size_t)HID * HID, b2, amaxR, 1);
    gemm_seg_k<<<nwg, 256, 0, stream>>>(h01, h11, h00, h10, rsA, half, 1.0f,
                                        wt + (size_t)HID * HID, b2, amaxR, 1);
    { f16 *n00 = f0, *n10 = f1, *n01 = h00, *n11 = h10, *nf0 = h01, *nf1 = h11;
      h00 = n00; h10 = n10; h01 = n01; h11 = n11; f0 = nf0; f1 = nf1; }

    float* rcur = rsA;
    float  shift = 8.0f;   // stored h = true / (rcur * shift)

    for (int l = 1; l < NL; ++l) {
        convert_layer_k<<<dim3(HID / 64, HID / 64, 2), 256, 0, stream>>>(
            W1 + (size_t)l * HID * HID, W2 + (size_t)l * HID * HID, wt);
        float* rnew = (rcur == rsA) ? rsB : rsA;
        aggscale_k<<<(npad + 255) / 256, 256, 0, stream>>>(amaxR, rp, csr, rnew, nreal, npad);
        // agg col0: (h00,h01) -> (f0,f1); agg col1: (h10,h11) -> (h00,h01)
        aggcol_k<<<npad / 8, 256, 0, stream>>>(h00, h01, f0, f1, rcur, shift, rnew, rp, csr, nreal, half);
        aggcol_k<<<npad / 8, 256, 0, stream>>>(h10, h11, h00, h01, rcur, shift, rnew, rp, csr, nreal, half);
        f16 *g00 = f0, *g01 = f1, *g10 = h00, *g11 = h01, *x0 = h10, *x1 = h11;
        // GEMM1 (W1_l): half0 in(g00,g10)->out(x0,x1); half1 in(g01,g11)->out(g00,g10)
        gemm_seg_k<<<nwg, 256, 0, stream>>>(g00, g10, x0, x1, rnew, 0, 1.0f,
                                            wt, b1 + (size_t)l * HID, amaxR, 0);
        gemm_seg_k<<<nwg, 256, 0, stream>>>(g01, g11, g00, g10, rnew, half, 1.0f,
                                            wt, b1 + (size_t)l * HID, amaxR, 0);
        f16 *z00 = x0, *z10 = x1, *z01 = g00, *z11 = g10;   // free: g01,g11
        // GEMM2 (W2_l): records amax
        hipMemsetAsync(amaxR, 0, (size_t)npad * sizeof(float), stream);
        gemm_seg_k<<<nwg, 256, 0, stream>>>(z00, z10, g01, g11, rnew, 0, 8.0f,
                                            wt + (size_t)HID * HID, b2 + (size_t)l * HID, amaxR, 1);
        gemm_seg_k<<<nwg, 256, 0, stream>>>(z01, z11, z00, z10, rnew, half, 8.0f,
                                            wt + (size_t)HID * HID, b2 + (size_t)l * HID, amaxR, 1);
        h00 = g01; h10 = g11; h01 = z00; h11 = z10; f0 = g00; f1 = g10;
        rcur = rnew;
        shift = 64.0f;
    }

    pool_k<<<dim3(NG, HID / 256), 256, 0, stream>>>(h00, h01, h10, h11, rcur, shift, goff, pooled, half);
    final_mm_k<<<NG, 512, 0, stream>>>(pooled, goff, Wf, bf, out);
}

// Round 8
// 8961.878 us; speedup vs baseline: 2.1546x; 1.0430x over previous
//
#include <hip/hip_runtime.h>

#define HID 768
#define EMB 512
#define NG  64
#define FIN 5
#define NL  16
#define CB  384   // column block width (HID/2)
#define PSEG 16   // pooling segments per graph

typedef _Float16 f16;
typedef f16   f16x4 __attribute__((ext_vector_type(4)));
typedef f16   f16x8 __attribute__((ext_vector_type(8)));
typedef float f32x4 __attribute__((ext_vector_type(4)));

// ---------------- CSR build ----------------
__global__ void count_deg_k(const int* __restrict__ ei, int* __restrict__ deg, int E) {
    int e = blockIdx.x * 256 + threadIdx.x;
    if (e < E) atomicAdd(&deg[ei[E + e]], 1);
}

// batch is sorted: goff[g] = lower_bound(batch, g); no atomics
__global__ void goff_k(const int* __restrict__ batch, int* __restrict__ goff, int n) {
    int g = threadIdx.x;
    if (g > NG) return;
    if (g == NG) { goff[NG] = n; return; }
    int lo = 0, hi = n;
    while (lo < hi) { int mid = (lo + hi) >> 1; if (batch[mid] < g) lo = mid + 1; else hi = mid; }
    goff[g] = lo;
}

__global__ void scan_rowptr_k(const int* __restrict__ deg, int* __restrict__ rp,
                              int* __restrict__ cur, int n) {
    __shared__ int wsum[16];
    __shared__ int carry;
    int t = threadIdx.x, lane = t & 63, w = t >> 6;
    if (t == 0) carry = 0;
    __syncthreads();
    for (int base = 0; base < n; base += 4096) {
        int v[4]; int s = 0;
        #pragma unroll
        for (int q = 0; q < 4; ++q) { int i = base + t * 4 + q; v[q] = (i < n) ? deg[i] : 0; s += v[q]; }
        int tot = s;
        int sc = tot;
        #pragma unroll
        for (int off = 1; off < 64; off <<= 1) { int u = __shfl_up(sc, off); if (lane >= off) sc += u; }
        if (lane == 63) wsum[w] = sc;
        __syncthreads();
        if (t < 16) {
            int xw = wsum[t];
            #pragma unroll
            for (int off = 1; off < 16; off <<= 1) { int u = __shfl_up(xw, off); if (t >= off) xw += u; }
            wsum[t] = xw;
        }
        __syncthreads();
        int woff = (w > 0) ? wsum[w - 1] : 0;
        int excl = carry + woff + sc - tot;
        #pragma unroll
        for (int q = 0; q < 4; ++q) { int i = base + t * 4 + q; if (i < n) { rp[i] = excl; cur[i] = excl; } excl += v[q]; }
        __syncthreads();
        if (t == 0) carry += wsum[15];
        __syncthreads();
    }
    if (t == 0) rp[n] = carry;
}

__global__ void scatter_k(const int* __restrict__ ei, int* __restrict__ cur,
                          int* __restrict__ csr, int E) {
    int e = blockIdx.x * 256 + threadIdx.x;
    if (e < E) { int d = ei[E + e]; int pos = atomicAdd(&cur[d], 1); csr[pos] = ei[e]; }
}

// canonicalize neighbor order (atomic scatter order varies call-to-call)
__global__ void sort_csr_k(const int* __restrict__ rp, int* __restrict__ csr, int n) {
    int i = blockIdx.x * 256 + threadIdx.x;
    if (i >= n) return;
    int e0 = rp[i], e1 = rp[i + 1];
    for (int a = e0 + 1; a < e1; ++a) {
        int v = csr[a];
        int b = a - 1;
        while (b >= e0 && csr[b] > v) { csr[b + 1] = csr[b]; --b; }
        csr[b + 1] = v;
    }
}

// ---- per-layer weight convert: W[k][n] fp32 -> wt[z][n][k] fp16 * 64 ----
__global__ void convert_layer_k(const float* __restrict__ Wa, const float* __restrict__ Wb,
                                f16* __restrict__ wt) {
    __shared__ float tile[64][65];
    const float* src = blockIdx.z ? Wb : Wa;
    f16* dst = wt + (size_t)blockIdx.z * HID * HID;
    int k0 = blockIdx.x * 64, n0 = blockIdx.y * 64;
    int t = threadIdx.x;
    #pragma unroll 4
    for (int i = 0; i < 16; ++i) {
        int r = (t >> 6) + i * 4;
        tile[r][t & 63] = src[(size_t)(k0 + r) * HID + n0 + (t & 63)];
    }
    __syncthreads();
    #pragma unroll 4
    for (int i = 0; i < 16; ++i) {
        int r = (t >> 6) + i * 4;
        dst[(size_t)(n0 + r) * HID + k0 + (t & 63)] = (f16)(tile[t & 63][r] * 64.0f);
    }
}

// ---- layer-0 folding ----
__global__ void make_wp1_k(const float* __restrict__ Wp, const float* __restrict__ bp,
                           const float* __restrict__ W1_0, float* __restrict__ wp1) {
    int nn = blockIdx.x * 256 + threadIdx.x;
    if (nn >= HID) return;
    float acc[6] = {0, 0, 0, 0, 0, 0};
    for (int j = 0; j < HID; ++j) {
        float wj = W1_0[(size_t)j * HID + nn];
        #pragma unroll
        for (int k = 0; k < FIN; ++k) acc[k] += Wp[k * HID + j] * wj;
        acc[5] += bp[j] * wj;
    }
    #pragma unroll
    for (int k = 0; k < 6; ++k) wp1[k * HID + nn] = acc[k];
}

__device__ __forceinline__ void row_scale(float amax, float& sc, float& rs) {
    int ex = 10;
    if (amax > 0.0f) frexpf(amax, &ex);
    int sh = 10 - ex;
    sh = sh > 120 ? 120 : (sh < -120 ? -120 : sh);
    sc = ldexpf(1.0f, sh);
    rs = ldexpf(1.0f, -sh);
}

// ---- fused layer0: z = relu(xagg@wp1 + (deg+1)*bpW1 + b1_0); writes 4 h-slots ----
__global__ __launch_bounds__(256) void fused_l0_k(
    const float* __restrict__ x, const int* __restrict__ rp, const int* __restrict__ csr,
    const float* __restrict__ wp1, const float* __restrict__ b1_0,
    f16* __restrict__ h00, f16* __restrict__ h01,   // col0: half0, half1
    f16* __restrict__ h10, f16* __restrict__ h11,   // col1: half0, half1
    float* __restrict__ rs_out, int nreal, int half) {
    __shared__ float w[7 * HID];
    for (int idx = threadIdx.x; idx < 7 * HID; idx += 256)
        w[idx] = (idx < 6 * HID) ? wp1[idx] : b1_0[idx - 6 * HID];
    __syncthreads();
    int node = blockIdx.x * 4 + (threadIdx.x >> 6);
    int lane = threadIdx.x & 63;
    int cblk = lane >> 5, ll = lane & 31;
    f16* base;
    int rloc;
    if (node < half) { base = cblk ? h10 : h00; rloc = node; }
    else             { base = cblk ? h11 : h01; rloc = node - half; }
    f16* orow = base + (size_t)rloc * CB + ll * 12;
    if (node >= nreal) {
        #pragma unroll
        for (int t = 0; t < 12; ++t) orow[t] = (f16)0.0f;
        if (lane == 0) rs_out[node] = 1.0f;
        return;
    }
    int e0 = rp[node], e1 = rp[node + 1];
    float xa[FIN];
    #pragma unroll
    for (int k = 0; k < FIN; ++k) xa[k] = x[(size_t)node * FIN + k];
    for (int e = e0; e < e1; ++e) {
        int j = csr[e];
        #pragma unroll
        for (int k = 0; k < FIN; ++k) xa[k] += x[(size_t)j * FIN + k];
    }
    float dp1 = (float)(e1 - e0 + 1);
    float a[12];
    #pragma unroll
    for (int t = 0; t < 12; ++t) {
        int c = lane * 12 + t;
        float v = w[5 * HID + c] * dp1 + w[6 * HID + c];
        #pragma unroll
        for (int k = 0; k < FIN; ++k) v += xa[k] * w[k * HID + c];
        a[t] = fmaxf(v, 0.0f);
    }
    float amax = 0.0f;
    #pragma unroll
    for (int t = 0; t < 12; ++t) amax = fmaxf(amax, fabsf(a[t]));
    #pragma unroll
    for (int off = 32; off; off >>= 1) amax = fmaxf(amax, __shfl_xor(amax, off));
    float sc, rs;
    row_scale(amax, sc, rs);
    if (lane == 0) rs_out[node] = rs;
    #pragma unroll
    for (int t = 0; t < 12; ++t) orow[t] = (f16)(a[t] * sc);
}

// ---- aggscale: fresh per-row output scale from recorded per-row true amax ----
__global__ void aggscale_k(const float* __restrict__ amaxR, const int* __restrict__ rp,
                           const int* __restrict__ csr, float* __restrict__ rsOut,
                           int nreal, int npad) {
    int i = blockIdx.x * 256 + threadIdx.x;
    if (i >= npad) return;
    if (i >= nreal) { rsOut[i] = 1.0f; return; }
    float M = amaxR[i];
    for (int e = rp[i]; e < rp[i + 1]; ++e) M = fmaxf(M, amaxR[csr[e]]);
    float r = 1.0f;
    if (M > 0.0f) {
        int ex; frexpf(M, &ex);
        int sh = ex - 9;                      // M / 2^sh in [256,512)
        sh = sh > 120 ? 120 : (sh < -120 ? -120 : sh);
        r = ldexpf(1.0f, sh);
    }
    rsOut[i] = r;
}

// ---- aggcol: one column block (2 row-half slots in, 2 out) ----
__global__ __launch_bounds__(256) void aggcol_k(
    const f16* __restrict__ s0, const f16* __restrict__ s1,
    f16* __restrict__ d0, f16* __restrict__ d1,
    const float* __restrict__ rsIn, float inShift,
    const float* __restrict__ rsOut,
    const int* __restrict__ rp, const int* __restrict__ csr, int nreal, int half) {
    int node = blockIdx.x * 8 + (threadIdx.x >> 5);
    int l = threadIdx.x & 31;
    f16* orow = (node < half ? d0 + (size_t)node * CB : d1 + (size_t)(node - half) * CB) + l * 12;
    if (node >= nreal) {
        #pragma unroll
        for (int t = 0; t < 12; ++t) orow[t] = (f16)0.0f;
        return;
    }
    float invOut = 1.0f / rsOut[node];
    float a[12];
    {
        float f = rsIn[node] * inShift * invOut;
        const f16* srow = (node < half ? s0 + (size_t)node * CB : s1 + (size_t)(node - half) * CB);
        const f16x4* p = (const f16x4*)(srow + l * 12);
        f16x4 v0 = p[0], v1 = p[1], v2 = p[2];
        #pragma unroll
        for (int t = 0; t < 4; ++t) {
            a[t] = (float)v0[t] * f; a[4 + t] = (float)v1[t] * f; a[8 + t] = (float)v2[t] * f;
        }
    }
    int e0 = rp[node], e1 = rp[node + 1];
    for (int e = e0; e < e1; ++e) {
        int j = csr[e];
        float f = rsIn[j] * inShift * invOut;
        const f16* srow = (j < half ? s0 + (size_t)j * CB : s1 + (size_t)(j - half) * CB);
        const f16x4* p = (const f16x4*)(srow + l * 12);
        f16x4 v0 = p[0], v1 = p[1], v2 = p[2];
        #pragma unroll
        for (int t = 0; t < 4; ++t) {
            a[t] += (float)v0[t] * f; a[4 + t] += (float)v1[t] * f; a[8 + t] += (float)v2[t] * f;
        }
    }
    f16x4 o0, o1, o2;
    #pragma unroll
    for (int t = 0; t < 4; ++t) {
        o0[t] = (f16)a[t]; o1[t] = (f16)a[4 + t]; o2[t] = (f16)a[8 + t];
    }
    f16x4* op = (f16x4*)orow;
    op[0] = o0; op[1] = o1; op[2] = o2;
}

// ---- m97-structure GEMM over one row-half segment, XCD-swizzled flat grid ----
__global__ __launch_bounds__(256) void gemm_seg_k(
    const f16* __restrict__ a0, const f16* __restrict__ a1,
    f16* __restrict__ c0, f16* __restrict__ c1,
    const float* __restrict__ rs, int rsOff, float shiftIn,
    const f16* __restrict__ wt, const float* __restrict__ bias,
    float* __restrict__ amaxR, int recAmax) {
    __shared__ f16 As[128 * 64];
    __shared__ f16 Bs[128 * 64];
    const int tid = threadIdx.x;
    const int lane = tid & 63;
    const int wid = tid >> 6;

    // bijective XCD swizzle (ERRATA #11 form), then n-fastest within chunk
    const int nwg = gridDim.x;
    const int q = nwg >> 3, r = nwg & 7;
    const int xcd = blockIdx.x & 7, loc = blockIdx.x >> 3;
    const int id2 = (xcd < r ? xcd * (q + 1) : r * (q + 1) + (xcd - r) * q) + loc;
    const int m0 = (id2 / 6) * 128;
    const int n0 = (id2 % 6) * 128;

    const int wr = (wid >> 1) * 64;
    const int wc = (wid & 1) * 64;

    f32x4 acc[4][4];
    #pragma unroll
    for (int m = 0; m < 4; ++m)
        #pragma unroll
        for (int n = 0; n < 4; ++n) acc[m][n] = (f32x4){0.f, 0.f, 0.f, 0.f};

    const int lrow = lane >> 3;       // 0..7 within 8-row chunk
    const int lcol = (lane & 7) * 8;  // 0..56

    for (int kt = 0; kt < 12; ++kt) {
        const f16* abase = (kt < 6) ? a0 : a1;
        const int kb = (kt < 6 ? kt : kt - 6) * 64;
        const int kw = kt * 64;
        #pragma unroll
        for (int i = 0; i < 4; ++i) {
            int chunk = i * 4 + wid;          // 0..15, wave-uniform
            int row = chunk * 8 + lrow;
            const f16* ga = abase + (size_t)(m0 + row) * CB + kb + lcol;
            __builtin_amdgcn_global_load_lds(
                (const __attribute__((address_space(1))) void*)ga,
                (__attribute__((address_space(3))) void*)(As + chunk * 512), 16, 0, 0);
            const f16* gb = wt + (size_t)(n0 + row) * HID + kw + lcol;
            __builtin_amdgcn_global_load_lds(
                (const __attribute__((address_space(1))) void*)gb,
                (__attribute__((address_space(3))) void*)(Bs + chunk * 512), 16, 0, 0);
        }
        __syncthreads();
        #pragma unroll
        for (int kk = 0; kk < 2; ++kk) {
            const int kf = kk * 32 + (lane >> 4) * 8;
            f16x8 af[4], bfr[4];
            #pragma unroll
            for (int m = 0; m < 4; ++m)
                af[m] = *(const f16x8*)(As + (wr + m * 16 + (lane & 15)) * 64 + kf);
            #pragma unroll
            for (int n = 0; n < 4; ++n)
                bfr[n] = *(const f16x8*)(Bs + (wc + n * 16 + (lane & 15)) * 64 + kf);
            #pragma unroll
            for (int m = 0; m < 4; ++m)
                #pragma unroll
                for (int n = 0; n < 4; ++n)
                    acc[m][n] = __builtin_amdgcn_mfma_f32_16x16x32_f16(af[m], bfr[n], acc[m][n], 0, 0, 0);
        }
        __syncthreads();
    }

    const int l15 = lane & 15, l4 = lane >> 4;
    const int cbase = n0 + wc + l15;
    const int rbase = m0 + wr + (l4 << 2);
    float rvv[16], rinvv[16], am[16];
    #pragma unroll
    for (int m = 0; m < 4; ++m)
        #pragma unroll
        for (int r2 = 0; r2 < 4; ++r2) {
            int row = rbase + m * 16 + r2;
            float rv = rs[rsOff + row] * shiftIn * 8.0f;
            rvv[m * 4 + r2] = rv;
            rinvv[m * 4 + r2] = 1.0f / rv;
            am[m * 4 + r2] = 0.0f;
        }
    #pragma unroll
    for (int n = 0; n < 4; ++n) {
        const int col = cbase + n * 16;
        const float bcol = bias[col];
        #pragma unroll
        for (int m = 0; m < 4; ++m) {
            #pragma unroll
            for (int r2 = 0; r2 < 4; ++r2) {
                const int row = rbase + m * 16 + r2;
                float v = acc[m][n][r2] * (1.0f / 512.0f) + bcol * rinvv[m * 4 + r2];
                v = fmaxf(v, 0.0f);
                am[m * 4 + r2] = fmaxf(am[m * 4 + r2], v);
                f16 h = (f16)v;
                if (col < CB) c0[(size_t)row * CB + col] = h;
                else          c1[(size_t)row * CB + col - CB] = h;
            }
        }
    }
    if (recAmax) {
        #pragma unroll
        for (int i = 0; i < 16; ++i) {
            float a = am[i];
            a = fmaxf(a, __shfl_xor(a, 1));
            a = fmaxf(a, __shfl_xor(a, 2));
            a = fmaxf(a, __shfl_xor(a, 4));
            a = fmaxf(a, __shfl_xor(a, 8));
            if (l15 == 0) {
                int row = rbase + (i >> 2) * 16 + (i & 3);
                atomicMax((unsigned int*)&amaxR[rsOff + row], __float_as_uint(a * rvv[i]));
            }
        }
    }
}

// ---- pooling stage 1: deterministic segmented partial sums.
// block = (graph g, col group c, segment s); each partial cell written by exactly one block.
__global__ __launch_bounds__(256) void pool1_k(
    const f16* __restrict__ h00, const f16* __restrict__ h01,
    const f16* __restrict__ h10, const f16* __restrict__ h11,
    const float* __restrict__ rs,
    const int* __restrict__ goff, float* __restrict__ partial, int half) {
    int g = blockIdx.x, c = blockIdx.y, s = blockIdx.z;
    int t = threadIdx.x;
    int col = c * 256 + t;
    int cb = col >= CB;
    int cc = cb ? col - CB : col;
    int i0 = goff[g], i1 = goff[g + 1];
    int len = i1 - i0;
    int s0 = i0 + (int)(((long long)len * s) / PSEG);
    int s1 = i0 + (int)(((long long)len * (s + 1)) / PSEG);
    float a = 0.0f;
    for (int i = s0; i < s1; ++i) {
        const f16* base = (i < half) ? (cb ? h10 : h00) : (cb ? h11 : h01);
        int r = (i < half) ? i : i - half;
        a += (float)base[(size_t)r * CB + cc] * rs[i];
    }
    partial[((size_t)(g * PSEG + s)) * HID + col] = a;
}

// ---- pooling stage 2: fixed-order sum of PSEG partials ----
__global__ __launch_bounds__(256) void pool2_k(const float* __restrict__ partial,
                                               float shift, float* __restrict__ pooled) {
    int g = blockIdx.x;
    int col = blockIdx.y * 256 + threadIdx.x;
    float a = 0.0f;
    #pragma unroll
    for (int s = 0; s < PSEG; ++s)
        a += partial[((size_t)(g * PSEG + s)) * HID + col];
    pooled[g * HID + col] = a * shift;
}

__global__ __launch_bounds__(512) void final_mm_k(const float* __restrict__ pooled,
                                                  const int* __restrict__ goff,
                                                  const float* __restrict__ Wf,
                                                  const float* __restrict__ bf,
                                                  float* __restrict__ out) {
    __shared__ float ps[HID];
    int g = blockIdx.x;
    int t = threadIdx.x;
    float inv = 1.0f / fmaxf((float)(goff[g + 1] - goff[g]), 1.0f);
    for (int k = t; k < HID; k += 512) ps[k] = pooled[g * HID + k] * inv;
    __syncthreads();
    float acc = bf[t];
    for (int k = 0; k < HID; ++k) acc += ps[k] * Wf[(size_t)k * EMB + t];
    out[(size_t)g * EMB + t] = acc;
}

__global__ void sentinel_k(float* __restrict__ out, int n, float v) {
    int i = blockIdx.x * 256 + threadIdx.x;
    if (i < n) out[i] = v;
}

// ---------------- launch ----------------
extern "C" void kernel_launch(void* const* d_in, const int* in_sizes, int n_in,
                              void* d_out, int out_size, void* d_ws, size_t ws_size,
                              hipStream_t stream) {
    const float* x    = (const float*)d_in[0];
    const int*   ei   = (const int*)d_in[1];
    const int*   batch= (const int*)d_in[2];
    const float* Wp   = (const float*)d_in[3];
    const float* bp   = (const float*)d_in[4];
    const float* W1   = (const float*)d_in[5];
    const float* b1   = (const float*)d_in[6];
    const float* W2   = (const float*)d_in[7];
    const float* b2   = (const float*)d_in[8];
    const float* Wf   = (const float*)d_in[9];
    const float* bf   = (const float*)d_in[10];
    float* out = (float*)d_out;

    const int nreal = in_sizes[0] / FIN;              // 100000
    const int E     = in_sizes[1] / 2;                // 200000
    const int npad  = ((nreal + 255) / 256) * 256;    // 100352
    const int half  = npad / 2;                       // 50176 (392 tiles of 128)
    const size_t slotsz = (size_t)half * CB;          // f16 elements per slot

    char* p = (char*)d_ws;
    auto alloc = [&](size_t bytes) -> char* {
        char* r = p; p += (bytes + 511) & ~(size_t)511; return r;
    };
    f16* slot[6];
    for (int i = 0; i < 6; ++i) slot[i] = (f16*)alloc(slotsz * sizeof(f16));
    f16*   wt   = (f16*)  alloc((size_t)2 * HID * HID * sizeof(f16));
    float* rsA  = (float*)alloc((size_t)npad * sizeof(float));
    float* rsB  = (float*)alloc((size_t)npad * sizeof(float));
    float* amaxR= (float*)alloc((size_t)npad * sizeof(float));
    int*   rp   = (int*)  alloc((size_t)(npad + 1) * sizeof(int));
    int*   csr  = (int*)  alloc((size_t)E * sizeof(int));
    float* wp1  = (float*)alloc((size_t)6 * HID * sizeof(float));
    int*   goff = (int*)  alloc((size_t)(NG + 1) * sizeof(int));
    float* pooled = (float*)alloc((size_t)NG * HID * sizeof(float));
    float* partial = (float*)alloc((size_t)NG * PSEG * HID * sizeof(float));
    char*  zstart = p;
    int*   deg  = (int*)  alloc((size_t)npad * sizeof(int));
    int*   cur  = (int*)  alloc((size_t)npad * sizeof(int));
    size_t zbytes = (size_t)(p - zstart);
    size_t need  = (size_t)(p - (char*)d_ws);

    if (need > ws_size) {
        sentinel_k<<<(out_size + 255) / 256, 256, 0, stream>>>(out, out_size, (float)(ws_size >> 20));
        return;
    }

    hipMemsetAsync(zstart, 0, zbytes, stream);

    count_deg_k  <<<(E + 255) / 256, 256, 0, stream>>>(ei, deg, E);
    goff_k       <<<1, 128, 0, stream>>>(batch, goff, nreal);
    scan_rowptr_k<<<1, 1024, 0, stream>>>(deg, rp, cur, nreal);
    scatter_k    <<<(E + 255) / 256, 256, 0, stream>>>(ei, cur, csr, E);
    sort_csr_k   <<<(nreal + 255) / 256, 256, 0, stream>>>(rp, csr, nreal);

    make_wp1_k<<<(HID + 255) / 256, 256, 0, stream>>>(Wp, bp, W1, wp1);

    // h slots: h00,h01 = col0 halves; h10,h11 = col1 halves; f0,f1 spare
    f16 *h00 = slot[0], *h01 = slot[1], *h10 = slot[2], *h11 = slot[3];
    f16 *f0 = slot[4], *f1 = slot[5];

    fused_l0_k<<<npad / 4, 256, 0, stream>>>(x, rp, csr, wp1, b1, h00, h01, h10, h11, rsA, nreal, half);

    const int nwg = (half / 128) * (HID / 128);   // 392*6 = 2352

    // layer 0 second matmul (W2[0]): row-half rotation, records amax
    convert_layer_k<<<dim3(HID / 64, HID / 64, 2), 256, 0, stream>>>(W1, W2, wt);
    hipMemsetAsync(amaxR, 0, (size_t)npad * sizeof(float), stream);
    gemm_seg_k<<<nwg, 256, 0, stream>>>(h00, h10, f0, f1, rsA, 0, 1.0f,
                                        wt + (size_t)HID * HID, b2, amaxR, 1);
    gemm_seg_k<<<nwg, 256, 0, stream>>>(h01, h11, h00, h10, rsA, half, 1.0f,
                                        wt + (size_t)HID * HID, b2, amaxR, 1);
    { f16 *n00 = f0, *n10 = f1, *n01 = h00, *n11 = h10, *nf0 = h01, *nf1 = h11;
      h00 = n00; h10 = n10; h01 = n01; h11 = n11; f0 = nf0; f1 = nf1; }

    float* rcur = rsA;
    float  shift = 8.0f;   // stored h = true / (rcur * shift)

    for (int l = 1; l < NL; ++l) {
        convert_layer_k<<<dim3(HID / 64, HID / 64, 2), 256, 0, stream>>>(
            W1 + (size_t)l * HID * HID, W2 + (size_t)l * HID * HID, wt);
        float* rnew = (rcur == rsA) ? rsB : rsA;
        aggscale_k<<<(npad + 255) / 256, 256, 0, stream>>>(amaxR, rp, csr, rnew, nreal, npad);
        // agg col0: (h00,h01) -> (f0,f1); agg col1: (h10,h11) -> (h00,h01)
        aggcol_k<<<npad / 8, 256, 0, stream>>>(h00, h01, f0, f1, rcur, shift, rnew, rp, csr, nreal, half);
        aggcol_k<<<npad / 8, 256, 0, stream>>>(h10, h11, h00, h01, rcur, shift, rnew, rp, csr, nreal, half);
        f16 *g00 = f0, *g01 = f1, *g10 = h00, *g11 = h01, *x0 = h10, *x1 = h11;
        // GEMM1 (W1_l): half0 in(g00,g10)->out(x0,x1); half1 in(g01,g11)->out(g00,g10)
        gemm_seg_k<<<nwg, 256, 0, stream>>>(g00, g10, x0, x1, rnew, 0, 1.0f,
                                            wt, b1 + (size_t)l * HID, amaxR, 0);
        gemm_seg_k<<<nwg, 256, 0, stream>>>(g01, g11, g00, g10, rnew, half, 1.0f,
                                            wt, b1 + (size_t)l * HID, amaxR, 0);
        f16 *z00 = x0, *z10 = x1, *z01 = g00, *z11 = g10;   // free: g01,g11
        // GEMM2 (W2_l): records amax
        hipMemsetAsync(amaxR, 0, (size_t)npad * sizeof(float), stream);
        gemm_seg_k<<<nwg, 256, 0, stream>>>(z00, z10, g01, g11, rnew, 0, 8.0f,
                                            wt + (size_t)HID * HID, b2 + (size_t)l * HID, amaxR, 1);
        gemm_seg_k<<<nwg, 256, 0, stream>>>(z01, z11, z00, z10, rnew, half, 8.0f,
                                            wt + (size_t)HID * HID, b2 + (size_t)l * HID, amaxR, 1);
        h00 = g01; h10 = g11; h01 = z00; h11 = z10; f0 = g00; f1 = g10;
        rcur = rnew;
        shift = 64.0f;
    }

    pool1_k<<<dim3(NG, HID / 256, PSEG), 256, 0, stream>>>(h00, h01, h10, h11, rcur, goff, partial, half);
    pool2_k<<<dim3(NG, HID / 256), 256, 0, stream>>>(partial, shift, pooled);
    final_mm_k<<<NG, 512, 0, stream>>>(pooled, goff, Wf, bf, out);
}

// Round 9
// 8416.507 us; speedup vs baseline: 2.2942x; 1.0648x over previous
//
#include <hip/hip_runtime.h>

#define HID 768
#define EMB 512
#define NG  64
#define FIN 5
#define NL  16
#define CB  384   // column block width (HID/2)
#define PSEG 16   // pooling segments per graph

typedef _Float16 f16;
typedef f16   f16x4 __attribute__((ext_vector_type(4)));
typedef f16   f16x8 __attribute__((ext_vector_type(8)));
typedef float f32x4 __attribute__((ext_vector_type(4)));

// ---------------- CSR build ----------------
__global__ void count_deg_k(const int* __restrict__ ei, int* __restrict__ deg, int E) {
    int e = blockIdx.x * 256 + threadIdx.x;
    if (e < E) atomicAdd(&deg[ei[E + e]], 1);
}

// batch is sorted: goff[g] = lower_bound(batch, g); no atomics
__global__ void goff_k(const int* __restrict__ batch, int* __restrict__ goff, int n) {
    int g = threadIdx.x;
    if (g > NG) return;
    if (g == NG) { goff[NG] = n; return; }
    int lo = 0, hi = n;
    while (lo < hi) { int mid = (lo + hi) >> 1; if (batch[mid] < g) lo = mid + 1; else hi = mid; }
    goff[g] = lo;
}

__global__ void scan_rowptr_k(const int* __restrict__ deg, int* __restrict__ rp,
                              int* __restrict__ cur, int n) {
    __shared__ int wsum[16];
    __shared__ int carry;
    int t = threadIdx.x, lane = t & 63, w = t >> 6;
    if (t == 0) carry = 0;
    __syncthreads();
    for (int base = 0; base < n; base += 4096) {
        int v[4]; int s = 0;
        #pragma unroll
        for (int q = 0; q < 4; ++q) { int i = base + t * 4 + q; v[q] = (i < n) ? deg[i] : 0; s += v[q]; }
        int tot = s;
        int sc = tot;
        #pragma unroll
        for (int off = 1; off < 64; off <<= 1) { int u = __shfl_up(sc, off); if (lane >= off) sc += u; }
        if (lane == 63) wsum[w] = sc;
        __syncthreads();
        if (t < 16) {
            int xw = wsum[t];
            #pragma unroll
            for (int off = 1; off < 16; off <<= 1) { int u = __shfl_up(xw, off); if (t >= off) xw += u; }
            wsum[t] = xw;
        }
        __syncthreads();
        int woff = (w > 0) ? wsum[w - 1] : 0;
        int excl = carry + woff + sc - tot;
        #pragma unroll
        for (int q = 0; q < 4; ++q) { int i = base + t * 4 + q; if (i < n) { rp[i] = excl; cur[i] = excl; } excl += v[q]; }
        __syncthreads();
        if (t == 0) carry += wsum[15];
        __syncthreads();
    }
    if (t == 0) rp[n] = carry;
}

__global__ void scatter_k(const int* __restrict__ ei, int* __restrict__ cur,
                          int* __restrict__ csr, int E) {
    int e = blockIdx.x * 256 + threadIdx.x;
    if (e < E) { int d = ei[E + e]; int pos = atomicAdd(&cur[d], 1); csr[pos] = ei[e]; }
}

// canonicalize neighbor order (atomic scatter order varies call-to-call)
__global__ void sort_csr_k(const int* __restrict__ rp, int* __restrict__ csr, int n) {
    int i = blockIdx.x * 256 + threadIdx.x;
    if (i >= n) return;
    int e0 = rp[i], e1 = rp[i + 1];
    for (int a = e0 + 1; a < e1; ++a) {
        int v = csr[a];
        int b = a - 1;
        while (b >= e0 && csr[b] > v) { csr[b + 1] = csr[b]; --b; }
        csr[b + 1] = v;
    }
}

// ---- per-layer weight convert: W[k][n] fp32 -> wt[z][n][k] fp16 * 64 ----
__global__ void convert_layer_k(const float* __restrict__ Wa, const float* __restrict__ Wb,
                                f16* __restrict__ wt) {
    __shared__ float tile[64][65];
    const float* src = blockIdx.z ? Wb : Wa;
    f16* dst = wt + (size_t)blockIdx.z * HID * HID;
    int k0 = blockIdx.x * 64, n0 = blockIdx.y * 64;
    int t = threadIdx.x;
    #pragma unroll 4
    for (int i = 0; i < 16; ++i) {
        int r = (t >> 6) + i * 4;
        tile[r][t & 63] = src[(size_t)(k0 + r) * HID + n0 + (t & 63)];
    }
    __syncthreads();
    #pragma unroll 4
    for (int i = 0; i < 16; ++i) {
        int r = (t >> 6) + i * 4;
        dst[(size_t)(n0 + r) * HID + k0 + (t & 63)] = (f16)(tile[t & 63][r] * 64.0f);
    }
}

// ---- layer-0 folding ----
__global__ void make_wp1_k(const float* __restrict__ Wp, const float* __restrict__ bp,
                           const float* __restrict__ W1_0, float* __restrict__ wp1) {
    int nn = blockIdx.x * 256 + threadIdx.x;
    if (nn >= HID) return;
    float acc[6] = {0, 0, 0, 0, 0, 0};
    for (int j = 0; j < HID; ++j) {
        float wj = W1_0[(size_t)j * HID + nn];
        #pragma unroll
        for (int k = 0; k < FIN; ++k) acc[k] += Wp[k * HID + j] * wj;
        acc[5] += bp[j] * wj;
    }
    #pragma unroll
    for (int k = 0; k < 6; ++k) wp1[k * HID + nn] = acc[k];
}

__device__ __forceinline__ void row_scale(float amax, float& sc, float& rs) {
    int ex = 10;
    if (amax > 0.0f) frexpf(amax, &ex);
    int sh = 10 - ex;
    sh = sh > 120 ? 120 : (sh < -120 ? -120 : sh);
    sc = ldexpf(1.0f, sh);
    rs = ldexpf(1.0f, -sh);
}

// ---- fused layer0: z = relu(xagg@wp1 + (deg+1)*bpW1 + b1_0); writes 4 h-slots ----
__global__ __launch_bounds__(256) void fused_l0_k(
    const float* __restrict__ x, const int* __restrict__ rp, const int* __restrict__ csr,
    const float* __restrict__ wp1, const float* __restrict__ b1_0,
    f16* __restrict__ h00, f16* __restrict__ h01,   // col0: half0, half1
    f16* __restrict__ h10, f16* __restrict__ h11,   // col1: half0, half1
    float* __restrict__ rs_out, int nreal, int half) {
    __shared__ float w[7 * HID];
    for (int idx = threadIdx.x; idx < 7 * HID; idx += 256)
        w[idx] = (idx < 6 * HID) ? wp1[idx] : b1_0[idx - 6 * HID];
    __syncthreads();
    int node = blockIdx.x * 4 + (threadIdx.x >> 6);
    int lane = threadIdx.x & 63;
    int cblk = lane >> 5, ll = lane & 31;
    f16* base;
    int rloc;
    if (node < half) { base = cblk ? h10 : h00; rloc = node; }
    else             { base = cblk ? h11 : h01; rloc = node - half; }
    f16* orow = base + (size_t)rloc * CB + ll * 12;
    if (node >= nreal) {
        #pragma unroll
        for (int t = 0; t < 12; ++t) orow[t] = (f16)0.0f;
        if (lane == 0) rs_out[node] = 1.0f;
        return;
    }
    int e0 = rp[node], e1 = rp[node + 1];
    float xa[FIN];
    #pragma unroll
    for (int k = 0; k < FIN; ++k) xa[k] = x[(size_t)node * FIN + k];
    for (int e = e0; e < e1; ++e) {
        int j = csr[e];
        #pragma unroll
        for (int k = 0; k < FIN; ++k) xa[k] += x[(size_t)j * FIN + k];
    }
    float dp1 = (float)(e1 - e0 + 1);
    float a[12];
    #pragma unroll
    for (int t = 0; t < 12; ++t) {
        int c = lane * 12 + t;
        float v = w[5 * HID + c] * dp1 + w[6 * HID + c];
        #pragma unroll
        for (int k = 0; k < FIN; ++k) v += xa[k] * w[k * HID + c];
        a[t] = fmaxf(v, 0.0f);
    }
    float amax = 0.0f;
    #pragma unroll
    for (int t = 0; t < 12; ++t) amax = fmaxf(amax, fabsf(a[t]));
    #pragma unroll
    for (int off = 32; off; off >>= 1) amax = fmaxf(amax, __shfl_xor(amax, off));
    float sc, rs;
    row_scale(amax, sc, rs);
    if (lane == 0) rs_out[node] = rs;
    #pragma unroll
    for (int t = 0; t < 12; ++t) orow[t] = (f16)(a[t] * sc);
}

// ---- aggscale: fresh per-row output scale from recorded per-row true amax ----
__global__ void aggscale_k(const float* __restrict__ amaxR, const int* __restrict__ rp,
                           const int* __restrict__ csr, float* __restrict__ rsOut,
                           int nreal, int npad) {
    int i = blockIdx.x * 256 + threadIdx.x;
    if (i >= npad) return;
    if (i >= nreal) { rsOut[i] = 1.0f; return; }
    float M = amaxR[i];
    for (int e = rp[i]; e < rp[i + 1]; ++e) M = fmaxf(M, amaxR[csr[e]]);
    float r = 1.0f;
    if (M > 0.0f) {
        int ex; frexpf(M, &ex);
        int sh = ex - 9;                      // M / 2^sh in [256,512)
        sh = sh > 120 ? 120 : (sh < -120 ? -120 : sh);
        r = ldexpf(1.0f, sh);
    }
    rsOut[i] = r;
}

// ---- aggcol: one column block (2 row-half slots in, 2 out) ----
__global__ __launch_bounds__(256) void aggcol_k(
    const f16* __restrict__ s0, const f16* __restrict__ s1,
    f16* __restrict__ d0, f16* __restrict__ d1,
    const float* __restrict__ rsIn, float inShift,
    const float* __restrict__ rsOut,
    const int* __restrict__ rp, const int* __restrict__ csr, int nreal, int half) {
    int node = blockIdx.x * 8 + (threadIdx.x >> 5);
    int l = threadIdx.x & 31;
    f16* orow = (node < half ? d0 + (size_t)node * CB : d1 + (size_t)(node - half) * CB) + l * 12;
    if (node >= nreal) {
        #pragma unroll
        for (int t = 0; t < 12; ++t) orow[t] = (f16)0.0f;
        return;
    }
    float invOut = 1.0f / rsOut[node];
    float a[12];
    {
        float f = rsIn[node] * inShift * invOut;
        const f16* srow = (node < half ? s0 + (size_t)node * CB : s1 + (size_t)(node - half) * CB);
        const f16x4* p = (const f16x4*)(srow + l * 12);
        f16x4 v0 = p[0], v1 = p[1], v2 = p[2];
        #pragma unroll
        for (int t = 0; t < 4; ++t) {
            a[t] = (float)v0[t] * f; a[4 + t] = (float)v1[t] * f; a[8 + t] = (float)v2[t] * f;
        }
    }
    int e0 = rp[node], e1 = rp[node + 1];
    for (int e = e0; e < e1; ++e) {
        int j = csr[e];
        float f = rsIn[j] * inShift * invOut;
        const f16* srow = (j < half ? s0 + (size_t)j * CB : s1 + (size_t)(j - half) * CB);
        const f16x4* p = (const f16x4*)(srow + l * 12);
        f16x4 v0 = p[0], v1 = p[1], v2 = p[2];
        #pragma unroll
        for (int t = 0; t < 4; ++t) {
            a[t] += (float)v0[t] * f; a[4 + t] += (float)v1[t] * f; a[8 + t] += (float)v2[t] * f;
        }
    }
    f16x4 o0, o1, o2;
    #pragma unroll
    for (int t = 0; t < 4; ++t) {
        o0[t] = (f16)a[t]; o1[t] = (f16)a[4 + t]; o2[t] = (f16)a[8 + t];
    }
    f16x4* op = (f16x4*)orow;
    op[0] = o0; op[1] = o1; op[2] = o2;
}

// ---- GEMM: 128x128 tile, BK=64, double-buffered LDS (T3-minimum 2-phase: stage k+1
// before compute k, ONE barrier per K-step), XCD-swizzled flat grid, LDS-staged
// coalesced C epilogue. ----
__global__ __launch_bounds__(256) void gemm_seg_k(
    const f16* __restrict__ a0, const f16* __restrict__ a1,
    f16* __restrict__ c0, f16* __restrict__ c1,
    const float* __restrict__ rs, int rsOff, float shiftIn,
    const f16* __restrict__ wt, const float* __restrict__ bias,
    float* __restrict__ amaxR, int recAmax) {
    __shared__ f16 lds[32768];            // 64 KB: two (As|Bs) buffers of 16384 f16
    __shared__ float rss[128], rsi[128];  // rs*shiftIn*8 and its reciprocal per tile row
    const int tid = threadIdx.x;
    const int lane = tid & 63;
    const int wid = tid >> 6;

    // bijective XCD swizzle (ERRATA #11 form), n-fastest within chunk
    const int nwg = gridDim.x;
    const int q = nwg >> 3, r = nwg & 7;
    const int xcd = blockIdx.x & 7, loc = blockIdx.x >> 3;
    const int id2 = (xcd < r ? xcd * (q + 1) : r * (q + 1) + (xcd - r) * q) + loc;
    const int m0 = (id2 / 6) * 128;
    const int n0 = (id2 % 6) * 128;

    if (tid < 128) {
        float rv = rs[rsOff + m0 + tid] * shiftIn * 8.0f;
        rss[tid] = rv;
        rsi[tid] = 1.0f / rv;
    }

    const int wr = (wid >> 1) * 64;
    const int wc = (wid & 1) * 64;
    const int lrow = lane >> 3;       // 0..7 within 8-row chunk
    const int lcol = (lane & 7) * 8;  // 0..56

    auto stage = [&](int kt, int buf) {
        const f16* abase = (kt < 6) ? a0 : a1;
        const int kb = (kt < 6 ? kt : kt - 6) * 64;
        const int kw = kt * 64;
        f16* As = lds + buf * 16384;
        f16* Bs = As + 8192;
        #pragma unroll
        for (int i = 0; i < 4; ++i) {
            int chunk = i * 4 + wid;          // wave-uniform
            int row = chunk * 8 + lrow;
            const f16* ga = abase + (size_t)(m0 + row) * CB + kb + lcol;
            __builtin_amdgcn_global_load_lds(
                (const __attribute__((address_space(1))) void*)ga,
                (__attribute__((address_space(3))) void*)(As + chunk * 512), 16, 0, 0);
            const f16* gb = wt + (size_t)(n0 + row) * HID + kw + lcol;
            __builtin_amdgcn_global_load_lds(
                (const __attribute__((address_space(1))) void*)gb,
                (__attribute__((address_space(3))) void*)(Bs + chunk * 512), 16, 0, 0);
        }
    };

    f32x4 acc[4][4];
    #pragma unroll
    for (int m = 0; m < 4; ++m)
        #pragma unroll
        for (int n = 0; n < 4; ++n) acc[m][n] = (f32x4){0.f, 0.f, 0.f, 0.f};

    stage(0, 0);
    __syncthreads();
    int cur = 0;
    for (int kt = 0; kt < 12; ++kt) {
        if (kt < 11) stage(kt + 1, cur ^ 1);   // prefetch overlaps this tile's compute
        const f16* As = lds + cur * 16384;
        const f16* Bs = As + 8192;
        #pragma unroll
        for (int kk = 0; kk < 2; ++kk) {
            const int kf = kk * 32 + (lane >> 4) * 8;
            f16x8 af[4], bfr[4];
            #pragma unroll
            for (int m = 0; m < 4; ++m)
                af[m] = *(const f16x8*)(As + (wr + m * 16 + (lane & 15)) * 64 + kf);
            #pragma unroll
            for (int n = 0; n < 4; ++n)
                bfr[n] = *(const f16x8*)(Bs + (wc + n * 16 + (lane & 15)) * 64 + kf);
            #pragma unroll
            for (int m = 0; m < 4; ++m)
                #pragma unroll
                for (int n = 0; n < 4; ++n)
                    acc[m][n] = __builtin_amdgcn_mfma_f32_16x16x32_f16(af[m], bfr[n], acc[m][n], 0, 0, 0);
        }
        __syncthreads();   // drains this iter's prefetch (had full MFMA phase to land)
        cur ^= 1;
    }

    // ---- epilogue: bias+relu+amax in regs, stage C in LDS [128][136], coalesced store ----
    const int l15 = lane & 15, l4 = lane >> 4;
    f16* cst = lds;   // 128*136 = 17408 f16 = 34.8 KB, safe after final barrier
    float am[16];
    #pragma unroll
    for (int i = 0; i < 16; ++i) am[i] = 0.0f;
    #pragma unroll
    for (int n = 0; n < 4; ++n) {
        const int colB = wc + n * 16 + l15;
        const float bcol = bias[n0 + colB];
        #pragma unroll
        for (int m = 0; m < 4; ++m) {
            #pragma unroll
            for (int r2 = 0; r2 < 4; ++r2) {
                const int rowB = wr + m * 16 + (l4 << 2) + r2;
                float v = acc[m][n][r2] * (1.0f / 512.0f) + bcol * rsi[rowB];
                v = fmaxf(v, 0.0f);
                am[m * 4 + r2] = fmaxf(am[m * 4 + r2], v);
                cst[rowB * 136 + colB] = (f16)v;
            }
        }
    }
    __syncthreads();
    {
        f16* Cw; int csub;
        if (n0 < CB) { Cw = c0; csub = n0; } else { Cw = c1; csub = n0 - CB; }
        #pragma unroll
        for (int i = 0; i < 8; ++i) {
            int rowB = wid * 32 + i * 4 + l4;
            f16x8 vv = *(const f16x8*)&cst[rowB * 136 + l15 * 8];
            *(f16x8*)&Cw[(size_t)(m0 + rowB) * CB + csub + l15 * 8] = vv;
        }
    }
    if (recAmax) {
        #pragma unroll
        for (int i = 0; i < 16; ++i) {
            float a = am[i];
            a = fmaxf(a, __shfl_xor(a, 1));
            a = fmaxf(a, __shfl_xor(a, 2));
            a = fmaxf(a, __shfl_xor(a, 4));
            a = fmaxf(a, __shfl_xor(a, 8));
            if (l15 == 0) {
                int rowB = wr + (i >> 2) * 16 + (l4 << 2) + (i & 3);
                atomicMax((unsigned int*)&amaxR[rsOff + m0 + rowB],
                          __float_as_uint(a * rss[rowB]));
            }
        }
    }
}

// ---- pooling stage 1: deterministic segmented partial sums ----
__global__ __launch_bounds__(256) void pool1_k(
    const f16* __restrict__ h00, const f16* __restrict__ h01,
    const f16* __restrict__ h10, const f16* __restrict__ h11,
    const float* __restrict__ rs,
    const int* __restrict__ goff, float* __restrict__ partial, int half) {
    int g = blockIdx.x, c = blockIdx.y, s = blockIdx.z;
    int t = threadIdx.x;
    int col = c * 256 + t;
    int cb = col >= CB;
    int cc = cb ? col - CB : col;
    int i0 = goff[g], i1 = goff[g + 1];
    int len = i1 - i0;
    int s0 = i0 + (int)(((long long)len * s) / PSEG);
    int s1 = i0 + (int)(((long long)len * (s + 1)) / PSEG);
    float a = 0.0f;
    for (int i = s0; i < s1; ++i) {
        const f16* base = (i < half) ? (cb ? h10 : h00) : (cb ? h11 : h01);
        int r = (i < half) ? i : i - half;
        a += (float)base[(size_t)r * CB + cc] * rs[i];
    }
    partial[((size_t)(g * PSEG + s)) * HID + col] = a;
}

// ---- pooling stage 2: fixed-order sum of PSEG partials ----
__global__ __launch_bounds__(256) void pool2_k(const float* __restrict__ partial,
                                               float shift, float* __restrict__ pooled) {
    int g = blockIdx.x;
    int col = blockIdx.y * 256 + threadIdx.x;
    float a = 0.0f;
    #pragma unroll
    for (int s = 0; s < PSEG; ++s)
        a += partial[((size_t)(g * PSEG + s)) * HID + col];
    pooled[g * HID + col] = a * shift;
}

__global__ __launch_bounds__(512) void final_mm_k(const float* __restrict__ pooled,
                                                  const int* __restrict__ goff,
                                                  const float* __restrict__ Wf,
                                                  const float* __restrict__ bf,
                                                  float* __restrict__ out) {
    __shared__ float ps[HID];
    int g = blockIdx.x;
    int t = threadIdx.x;
    float inv = 1.0f / fmaxf((float)(goff[g + 1] - goff[g]), 1.0f);
    for (int k = t; k < HID; k += 512) ps[k] = pooled[g * HID + k] * inv;
    __syncthreads();
    float acc = bf[t];
    for (int k = 0; k < HID; ++k) acc += ps[k] * Wf[(size_t)k * EMB + t];
    out[(size_t)g * EMB + t] = acc;
}

__global__ void sentinel_k(float* __restrict__ out, int n, float v) {
    int i = blockIdx.x * 256 + threadIdx.x;
    if (i < n) out[i] = v;
}

// ---------------- launch ----------------
extern "C" void kernel_launch(void* const* d_in, const int* in_sizes, int n_in,
                              void* d_out, int out_size, void* d_ws, size_t ws_size,
                              hipStream_t stream) {
    const float* x    = (const float*)d_in[0];
    const int*   ei   = (const int*)d_in[1];
    const int*   batch= (const int*)d_in[2];
    const float* Wp   = (const float*)d_in[3];
    const float* bp   = (const float*)d_in[4];
    const float* W1   = (const float*)d_in[5];
    const float* b1   = (const float*)d_in[6];
    const float* W2   = (const float*)d_in[7];
    const float* b2   = (const float*)d_in[8];
    const float* Wf   = (const float*)d_in[9];
    const float* bf   = (const float*)d_in[10];
    float* out = (float*)d_out;

    const int nreal = in_sizes[0] / FIN;              // 100000
    const int E     = in_sizes[1] / 2;                // 200000
    const int npad  = ((nreal + 255) / 256) * 256;    // 100352
    const int half  = npad / 2;                       // 50176 (392 tiles of 128)
    const size_t slotsz = (size_t)half * CB;          // f16 elements per slot

    char* p = (char*)d_ws;
    auto alloc = [&](size_t bytes) -> char* {
        char* r = p; p += (bytes + 511) & ~(size_t)511; return r;
    };
    f16* slot[6];
    for (int i = 0; i < 6; ++i) slot[i] = (f16*)alloc(slotsz * sizeof(f16));
    f16*   wt   = (f16*)  alloc((size_t)2 * HID * HID * sizeof(f16));
    float* rsA  = (float*)alloc((size_t)npad * sizeof(float));
    float* rsB  = (float*)alloc((size_t)npad * sizeof(float));
    float* amaxR= (float*)alloc((size_t)npad * sizeof(float));
    int*   rp   = (int*)  alloc((size_t)(npad + 1) * sizeof(int));
    int*   csr  = (int*)  alloc((size_t)E * sizeof(int));
    float* wp1  = (float*)alloc((size_t)6 * HID * sizeof(float));
    int*   goff = (int*)  alloc((size_t)(NG + 1) * sizeof(int));
    float* pooled = (float*)alloc((size_t)NG * HID * sizeof(float));
    float* partial = (float*)alloc((size_t)NG * PSEG * HID * sizeof(float));
    char*  zstart = p;
    int*   deg  = (int*)  alloc((size_t)npad * sizeof(int));
    int*   cur  = (int*)  alloc((size_t)npad * sizeof(int));
    size_t zbytes = (size_t)(p - zstart);
    size_t need  = (size_t)(p - (char*)d_ws);

    if (need > ws_size) {
        sentinel_k<<<(out_size + 255) / 256, 256, 0, stream>>>(out, out_size, (float)(ws_size >> 20));
        return;
    }

    hipMemsetAsync(zstart, 0, zbytes, stream);

    count_deg_k  <<<(E + 255) / 256, 256, 0, stream>>>(ei, deg, E);
    goff_k       <<<1, 128, 0, stream>>>(batch, goff, nreal);
    scan_rowptr_k<<<1, 1024, 0, stream>>>(deg, rp, cur, nreal);
    scatter_k    <<<(E + 255) / 256, 256, 0, stream>>>(ei, cur, csr, E);
    sort_csr_k   <<<(nreal + 255) / 256, 256, 0, stream>>>(rp, csr, nreal);

    make_wp1_k<<<(HID + 255) / 256, 256, 0, stream>>>(Wp, bp, W1, wp1);

    // h slots: h00,h01 = col0 halves; h10,h11 = col1 halves; f0,f1 spare
    f16 *h00 = slot[0], *h01 = slot[1], *h10 = slot[2], *h11 = slot[3];
    f16 *f0 = slot[4], *f1 = slot[5];

    fused_l0_k<<<npad / 4, 256, 0, stream>>>(x, rp, csr, wp1, b1, h00, h01, h10, h11, rsA, nreal, half);

    const int nwg = (half / 128) * (HID / 128);   // 392*6 = 2352

    // layer 0 second matmul (W2[0]): row-half rotation, records amax
    convert_layer_k<<<dim3(HID / 64, HID / 64, 2), 256, 0, stream>>>(W1, W2, wt);
    hipMemsetAsync(amaxR, 0, (size_t)npad * sizeof(float), stream);
    gemm_seg_k<<<nwg, 256, 0, stream>>>(h00, h10, f0, f1, rsA, 0, 1.0f,
                                        wt + (size_t)HID * HID, b2, amaxR, 1);
    gemm_seg_k<<<nwg, 256, 0, stream>>>(h01, h11, h00, h10, rsA, half, 1.0f,
                                        wt + (size_t)HID * HID, b2, amaxR, 1);
    { f16 *n00 = f0, *n10 = f1, *n01 = h00, *n11 = h10, *nf0 = h01, *nf1 = h11;
      h00 = n00; h10 = n10; h01 = n01; h11 = n11; f0 = nf0; f1 = nf1; }

    float* rcur = rsA;
    float  shift = 8.0f;   // stored h = true / (rcur * shift)

    for (int l = 1; l < NL; ++l) {
        convert_layer_k<<<dim3(HID / 64, HID / 64, 2), 256, 0, stream>>>(
            W1 + (size_t)l * HID * HID, W2 + (size_t)l * HID * HID, wt);
        float* rnew = (rcur == rsA) ? rsB : rsA;
        aggscale_k<<<(npad + 255) / 256, 256, 0, stream>>>(amaxR, rp, csr, rnew, nreal, npad);
        // agg col0: (h00,h01) -> (f0,f1); agg col1: (h10,h11) -> (h00,h01)
        aggcol_k<<<npad / 8, 256, 0, stream>>>(h00, h01, f0, f1, rcur, shift, rnew, rp, csr, nreal, half);
        aggcol_k<<<npad / 8, 256, 0, stream>>>(h10, h11, h00, h01, rcur, shift, rnew, rp, csr, nreal, half);
        f16 *g00 = f0, *g01 = f1, *g10 = h00, *g11 = h01, *x0 = h10, *x1 = h11;
        // GEMM1 (W1_l): half0 in(g00,g10)->out(x0,x1); half1 in(g01,g11)->out(g00,g10)
        gemm_seg_k<<<nwg, 256, 0, stream>>>(g00, g10, x0, x1, rnew, 0, 1.0f,
                                            wt, b1 + (size_t)l * HID, amaxR, 0);
        gemm_seg_k<<<nwg, 256, 0, stream>>>(g01, g11, g00, g10, rnew, half, 1.0f,
                                            wt, b1 + (size_t)l * HID, amaxR, 0);
        f16 *z00 = x0, *z10 = x1, *z01 = g00, *z11 = g10;   // free: g01,g11
        // GEMM2 (W2_l): records amax
        hipMemsetAsync(amaxR, 0, (size_t)npad * sizeof(float), stream);
        gemm_seg_k<<<nwg, 256, 0, stream>>>(z00, z10, g01, g11, rnew, 0, 8.0f,
                                            wt + (size_t)HID * HID, b2 + (size_t)l * HID, amaxR, 1);
        gemm_seg_k<<<nwg, 256, 0, stream>>>(z01, z11, z00, z10, rnew, half, 8.0f,
                                            wt + (size_t)HID * HID, b2 + (size_t)l * HID, amaxR, 1);
        h00 = g01; h10 = g11; h01 = z00; h11 = z10; f0 = g00; f1 = g10;
        rcur = rnew;
        shift = 64.0f;
    }

    pool1_k<<<dim3(NG, HID / 256, PSEG), 256, 0, stream>>>(h00, h01, h10, h11, rcur, goff, partial, half);
    pool2_k<<<dim3(NG, HID / 256), 256, 0, stream>>>(partial, shift, pooled);
    final_mm_k<<<NG, 512, 0, stream>>>(pooled, goff, Wf, bf, out);
}

// Round 10
// 6623.523 us; speedup vs baseline: 2.9152x; 1.2707x over previous
//
#include <hip/hip_runtime.h>

#define HID 768
#define EMB 512
#define NG  64
#define FIN 5
#define NL  16
#define CB  384   // column block width (HID/2)
#define PSEG 16   // pooling segments per graph

typedef _Float16 f16;
typedef f16   f16x4 __attribute__((ext_vector_type(4)));
typedef f16   f16x8 __attribute__((ext_vector_type(8)));
typedef float f32x4 __attribute__((ext_vector_type(4)));

// ---------------- CSR build ----------------
__global__ void count_deg_k(const int* __restrict__ ei, int* __restrict__ deg, int E) {
    int e = blockIdx.x * 256 + threadIdx.x;
    if (e < E) atomicAdd(&deg[ei[E + e]], 1);
}

// batch is sorted: goff[g] = lower_bound(batch, g); no atomics
__global__ void goff_k(const int* __restrict__ batch, int* __restrict__ goff, int n) {
    int g = threadIdx.x;
    if (g > NG) return;
    if (g == NG) { goff[NG] = n; return; }
    int lo = 0, hi = n;
    while (lo < hi) { int mid = (lo + hi) >> 1; if (batch[mid] < g) lo = mid + 1; else hi = mid; }
    goff[g] = lo;
}

__global__ void scan_rowptr_k(const int* __restrict__ deg, int* __restrict__ rp,
                              int* __restrict__ cur, int n) {
    __shared__ int wsum[16];
    __shared__ int carry;
    int t = threadIdx.x, lane = t & 63, w = t >> 6;
    if (t == 0) carry = 0;
    __syncthreads();
    for (int base = 0; base < n; base += 4096) {
        int v[4]; int s = 0;
        #pragma unroll
        for (int q = 0; q < 4; ++q) { int i = base + t * 4 + q; v[q] = (i < n) ? deg[i] : 0; s += v[q]; }
        int tot = s;
        int sc = tot;
        #pragma unroll
        for (int off = 1; off < 64; off <<= 1) { int u = __shfl_up(sc, off); if (lane >= off) sc += u; }
        if (lane == 63) wsum[w] = sc;
        __syncthreads();
        if (t < 16) {
            int xw = wsum[t];
            #pragma unroll
            for (int off = 1; off < 16; off <<= 1) { int u = __shfl_up(xw, off); if (t >= off) xw += u; }
            wsum[t] = xw;
        }
        __syncthreads();
        int woff = (w > 0) ? wsum[w - 1] : 0;
        int excl = carry + woff + sc - tot;
        #pragma unroll
        for (int q = 0; q < 4; ++q) { int i = base + t * 4 + q; if (i < n) { rp[i] = excl; cur[i] = excl; } excl += v[q]; }
        __syncthreads();
        if (t == 0) carry += wsum[15];
        __syncthreads();
    }
    if (t == 0) rp[n] = carry;
}

__global__ void scatter_k(const int* __restrict__ ei, int* __restrict__ cur,
                          int* __restrict__ csr, int E) {
    int e = blockIdx.x * 256 + threadIdx.x;
    if (e < E) { int d = ei[E + e]; int pos = atomicAdd(&cur[d], 1); csr[pos] = ei[e]; }
}

// canonicalize neighbor order (atomic scatter order varies call-to-call)
__global__ void sort_csr_k(const int* __restrict__ rp, int* __restrict__ csr, int n) {
    int i = blockIdx.x * 256 + threadIdx.x;
    if (i >= n) return;
    int e0 = rp[i], e1 = rp[i + 1];
    for (int a = e0 + 1; a < e1; ++a) {
        int v = csr[a];
        int b = a - 1;
        while (b >= e0 && csr[b] > v) { csr[b + 1] = csr[b]; --b; }
        csr[b + 1] = v;
    }
}

// ---- per-layer weight convert: W[k][n] fp32 -> wt[z][n][k] fp16 * 64 ----
__global__ void convert_layer_k(const float* __restrict__ Wa, const float* __restrict__ Wb,
                                f16* __restrict__ wt) {
    __shared__ float tile[64][65];
    const float* src = blockIdx.z ? Wb : Wa;
    f16* dst = wt + (size_t)blockIdx.z * HID * HID;
    int k0 = blockIdx.x * 64, n0 = blockIdx.y * 64;
    int t = threadIdx.x;
    #pragma unroll 4
    for (int i = 0; i < 16; ++i) {
        int r = (t >> 6) + i * 4;
        tile[r][t & 63] = src[(size_t)(k0 + r) * HID + n0 + (t & 63)];
    }
    __syncthreads();
    #pragma unroll 4
    for (int i = 0; i < 16; ++i) {
        int r = (t >> 6) + i * 4;
        dst[(size_t)(n0 + r) * HID + k0 + (t & 63)] = (f16)(tile[t & 63][r] * 64.0f);
    }
}

// ---- layer-0 folding ----
__global__ void make_wp1_k(const float* __restrict__ Wp, const float* __restrict__ bp,
                           const float* __restrict__ W1_0, float* __restrict__ wp1) {
    int nn = blockIdx.x * 256 + threadIdx.x;
    if (nn >= HID) return;
    float acc[6] = {0, 0, 0, 0, 0, 0};
    for (int j = 0; j < HID; ++j) {
        float wj = W1_0[(size_t)j * HID + nn];
        #pragma unroll
        for (int k = 0; k < FIN; ++k) acc[k] += Wp[k * HID + j] * wj;
        acc[5] += bp[j] * wj;
    }
    #pragma unroll
    for (int k = 0; k < 6; ++k) wp1[k * HID + nn] = acc[k];
}

__device__ __forceinline__ void row_scale(float amax, float& sc, float& rs) {
    int ex = 10;
    if (amax > 0.0f) frexpf(amax, &ex);
    int sh = 10 - ex;
    sh = sh > 120 ? 120 : (sh < -120 ? -120 : sh);
    sc = ldexpf(1.0f, sh);
    rs = ldexpf(1.0f, -sh);
}

// ---- fused layer0: z = relu(xagg@wp1 + (deg+1)*bpW1 + b1_0); writes 4 h-slots ----
__global__ __launch_bounds__(256) void fused_l0_k(
    const float* __restrict__ x, const int* __restrict__ rp, const int* __restrict__ csr,
    const float* __restrict__ wp1, const float* __restrict__ b1_0,
    f16* __restrict__ h00, f16* __restrict__ h01,   // col0: half0, half1
    f16* __restrict__ h10, f16* __restrict__ h11,   // col1: half0, half1
    float* __restrict__ rs_out, int nreal, int half) {
    __shared__ float w[7 * HID];
    for (int idx = threadIdx.x; idx < 7 * HID; idx += 256)
        w[idx] = (idx < 6 * HID) ? wp1[idx] : b1_0[idx - 6 * HID];
    __syncthreads();
    int node = blockIdx.x * 4 + (threadIdx.x >> 6);
    int lane = threadIdx.x & 63;
    int cblk = lane >> 5, ll = lane & 31;
    f16* base;
    int rloc;
    if (node < half) { base = cblk ? h10 : h00; rloc = node; }
    else             { base = cblk ? h11 : h01; rloc = node - half; }
    f16* orow = base + (size_t)rloc * CB + ll * 12;
    if (node >= nreal) {
        #pragma unroll
        for (int t = 0; t < 12; ++t) orow[t] = (f16)0.0f;
        if (lane == 0) rs_out[node] = 1.0f;
        return;
    }
    int e0 = rp[node], e1 = rp[node + 1];
    float xa[FIN];
    #pragma unroll
    for (int k = 0; k < FIN; ++k) xa[k] = x[(size_t)node * FIN + k];
    for (int e = e0; e < e1; ++e) {
        int j = csr[e];
        #pragma unroll
        for (int k = 0; k < FIN; ++k) xa[k] += x[(size_t)j * FIN + k];
    }
    float dp1 = (float)(e1 - e0 + 1);
    float a[12];
    #pragma unroll
    for (int t = 0; t < 12; ++t) {
        int c = lane * 12 + t;
        float v = w[5 * HID + c] * dp1 + w[6 * HID + c];
        #pragma unroll
        for (int k = 0; k < FIN; ++k) v += xa[k] * w[k * HID + c];
        a[t] = fmaxf(v, 0.0f);
    }
    float amax = 0.0f;
    #pragma unroll
    for (int t = 0; t < 12; ++t) amax = fmaxf(amax, fabsf(a[t]));
    #pragma unroll
    for (int off = 32; off; off >>= 1) amax = fmaxf(amax, __shfl_xor(amax, off));
    float sc, rs;
    row_scale(amax, sc, rs);
    if (lane == 0) rs_out[node] = rs;
    #pragma unroll
    for (int t = 0; t < 12; ++t) orow[t] = (f16)(a[t] * sc);
}

// ---- aggscale: fresh per-row output scale from recorded per-row true amax ----
__global__ void aggscale_k(const float* __restrict__ amaxR, const int* __restrict__ rp,
                           const int* __restrict__ csr, float* __restrict__ rsOut,
                           int nreal, int npad) {
    int i = blockIdx.x * 256 + threadIdx.x;
    if (i >= npad) return;
    if (i >= nreal) { rsOut[i] = 1.0f; return; }
    float M = amaxR[i];
    for (int e = rp[i]; e < rp[i + 1]; ++e) M = fmaxf(M, amaxR[csr[e]]);
    float r = 1.0f;
    if (M > 0.0f) {
        int ex; frexpf(M, &ex);
        int sh = ex - 9;                      // M / 2^sh in [256,512)
        sh = sh > 120 ? 120 : (sh < -120 ? -120 : sh);
        r = ldexpf(1.0f, sh);
    }
    rsOut[i] = r;
}

// ---- aggcol: one column block (2 row-half slots in, 2 out) ----
__global__ __launch_bounds__(256) void aggcol_k(
    const f16* __restrict__ s0, const f16* __restrict__ s1,
    f16* __restrict__ d0, f16* __restrict__ d1,
    const float* __restrict__ rsIn, float inShift,
    const float* __restrict__ rsOut,
    const int* __restrict__ rp, const int* __restrict__ csr, int nreal, int half) {
    int node = blockIdx.x * 8 + (threadIdx.x >> 5);
    int l = threadIdx.x & 31;
    f16* orow = (node < half ? d0 + (size_t)node * CB : d1 + (size_t)(node - half) * CB) + l * 12;
    if (node >= nreal) {
        #pragma unroll
        for (int t = 0; t < 12; ++t) orow[t] = (f16)0.0f;
        return;
    }
    float invOut = 1.0f / rsOut[node];
    float a[12];
    {
        float f = rsIn[node] * inShift * invOut;
        const f16* srow = (node < half ? s0 + (size_t)node * CB : s1 + (size_t)(node - half) * CB);
        const f16x4* p = (const f16x4*)(srow + l * 12);
        f16x4 v0 = p[0], v1 = p[1], v2 = p[2];
        #pragma unroll
        for (int t = 0; t < 4; ++t) {
            a[t] = (float)v0[t] * f; a[4 + t] = (float)v1[t] * f; a[8 + t] = (float)v2[t] * f;
        }
    }
    int e0 = rp[node], e1 = rp[node + 1];
    for (int e = e0; e < e1; ++e) {
        int j = csr[e];
        float f = rsIn[j] * inShift * invOut;
        const f16* srow = (j < half ? s0 + (size_t)j * CB : s1 + (size_t)(j - half) * CB);
        const f16x4* p = (const f16x4*)(srow + l * 12);
        f16x4 v0 = p[0], v1 = p[1], v2 = p[2];
        #pragma unroll
        for (int t = 0; t < 4; ++t) {
            a[t] += (float)v0[t] * f; a[4 + t] += (float)v1[t] * f; a[8 + t] += (float)v2[t] * f;
        }
    }
    f16x4 o0, o1, o2;
    #pragma unroll
    for (int t = 0; t < 4; ++t) {
        o0[t] = (f16)a[t]; o1[t] = (f16)a[4 + t]; o2[t] = (f16)a[8 + t];
    }
    f16x4* op = (f16x4*)orow;
    op[0] = o0; op[1] = o1; op[2] = o2;
}

// ---- GEMM: 128x128 tile, BK=64, 2 LDS buffers, counted-vmcnt split-phase pipeline
// (T4): per K-step {vmcnt(4);bar; read A-frags; stage A(t+1); vmcnt(4);bar;
// stage B(t+1); read B-frags + MFMA}. Loads never drain to 0 in the loop.
// T2 XOR swizzle (u^=row&7, 16B units): linear LDS dest + inverse-swizzled global
// source + swizzled ds_read. T5 setprio around MFMA. XCD-swizzled flat grid. ----
__global__ __launch_bounds__(256) void gemm_seg_k(
    const f16* __restrict__ a0, const f16* __restrict__ a1,
    f16* __restrict__ c0, f16* __restrict__ c1,
    const float* __restrict__ rs, int rsOff, float shiftIn,
    const f16* __restrict__ wt, const float* __restrict__ bias,
    float* __restrict__ amaxR, int recAmax) {
    __shared__ f16 lds[32768];            // 2 buffers: buf*16384 = A(8192 f16) | B(8192 f16)
    __shared__ float rss[128], rsi[128];
    const int tid = threadIdx.x;
    const int lane = tid & 63;
    const int wid = tid >> 6;

    // bijective XCD swizzle (ERRATA #11 form), n-fastest within chunk
    const int nwg = gridDim.x;
    const int q = nwg >> 3, r = nwg & 7;
    const int xcd = blockIdx.x & 7, loc = blockIdx.x >> 3;
    const int id2 = (xcd < r ? xcd * (q + 1) : r * (q + 1) + (xcd - r) * q) + loc;
    const int m0 = (id2 / 6) * 128;
    const int n0 = (id2 % 6) * 128;

    if (tid < 128) {
        float rv = rs[rsOff + m0 + tid] * shiftIn * 8.0f;
        rss[tid] = rv;
        rsi[tid] = 1.0f / rv;
    }

    const int wr = (wid >> 1) * 64;
    const int wc = (wid & 1) * 64;
    const int lrow = lane >> 3;                 // 0..7
    const int usrc = (lane & 7) ^ lrow;         // inverse-swizzled 16B unit for staging src
    const int l15 = lane & 15, l4 = lane >> 4;

    auto stageA = [&](int kt, int buf) {
        const f16* abase = (kt < 6) ? a0 : a1;
        const int kb = (kt < 6 ? kt : kt - 6) * 64;
        f16* As = lds + buf * 16384;
        #pragma unroll
        for (int i = 0; i < 4; ++i) {
            int chunk = i * 4 + wid;            // wave-uniform
            int row = chunk * 8 + lrow;
            const f16* ga = abase + (size_t)(m0 + row) * CB + kb + usrc * 8;
            __builtin_amdgcn_global_load_lds(
                (const __attribute__((address_space(1))) void*)ga,
                (__attribute__((address_space(3))) void*)(As + chunk * 512), 16, 0, 0);
        }
    };
    auto stageB = [&](int kt, int buf) {
        const int kw = kt * 64;
        f16* Bs = lds + buf * 16384 + 8192;
        #pragma unroll
        for (int i = 0; i < 4; ++i) {
            int chunk = i * 4 + wid;
            int row = chunk * 8 + lrow;
            const f16* gb = wt + (size_t)(n0 + row) * HID + kw + usrc * 8;
            __builtin_amdgcn_global_load_lds(
                (const __attribute__((address_space(1))) void*)gb,
                (__attribute__((address_space(3))) void*)(Bs + chunk * 512), 16, 0, 0);
        }
    };

    f32x4 acc[4][4];
    #pragma unroll
    for (int m = 0; m < 4; ++m)
        #pragma unroll
        for (int n = 0; n < 4; ++n) acc[m][n] = (f32x4){0.f, 0.f, 0.f, 0.f};

    // prologue: tile 0 into buf 0 (8 loads/wave outstanding)
    stageA(0, 0);
    stageB(0, 0);

    #pragma unroll
    for (int t = 0; t < 12; ++t) {
        const int c = t & 1, o = c ^ 1;
        const f16* Ac = lds + c * 16384;
        const f16* Bc = Ac + 8192;
        // s1: A(t) landed (oldest 4 of ≤8 outstanding); B(t) may stay in flight
        if (t == 11) asm volatile("s_waitcnt vmcnt(0)" ::: "memory");
        else         asm volatile("s_waitcnt vmcnt(4)" ::: "memory");
        __builtin_amdgcn_s_barrier();
        __builtin_amdgcn_sched_barrier(0);
        // s3: A fragments (swizzled read)
        f16x8 af[4][2];
        #pragma unroll
        for (int m = 0; m < 4; ++m) {
            int rowH = wr + m * 16 + l15;
            int sw = rowH & 7;
            #pragma unroll
            for (int kk = 0; kk < 2; ++kk) {
                int u = kk * 4 + l4;
                af[m][kk] = *(const f16x8*)(Ac + rowH * 64 + ((u ^ sw) << 3));
            }
        }
        // s4: stage A(t+1) into other buffer (its A region free since t-1)
        if (t < 11) stageA(t + 1, o);
        // s5: B(t) landed (drains oldest; leaves A(t+1) in flight)
        if (t == 11) asm volatile("s_waitcnt vmcnt(0)" ::: "memory");
        else         asm volatile("s_waitcnt vmcnt(4)" ::: "memory");
        __builtin_amdgcn_s_barrier();
        __builtin_amdgcn_sched_barrier(0);
        // s8: stage B(t+1) early so it lands during MFMA + next A-phase
        if (t < 11) stageB(t + 1, o);
        // s7: B fragments + MFMA cluster
        f16x8 bfr[4][2];
        #pragma unroll
        for (int n = 0; n < 4; ++n) {
            int rowB = wc + n * 16 + l15;
            int sw = rowB & 7;
            #pragma unroll
            for (int kk = 0; kk < 2; ++kk) {
                int u = kk * 4 + l4;
                bfr[n][kk] = *(const f16x8*)(Bc + rowB * 64 + ((u ^ sw) << 3));
            }
        }
        __builtin_amdgcn_s_setprio(1);
        #pragma unroll
        for (int kk = 0; kk < 2; ++kk)
            #pragma unroll
            for (int m = 0; m < 4; ++m)
                #pragma unroll
                for (int n = 0; n < 4; ++n)
                    acc[m][n] = __builtin_amdgcn_mfma_f32_16x16x32_f16(af[m][kk], bfr[n][kk], acc[m][n], 0, 0, 0);
        __builtin_amdgcn_s_setprio(0);
    }
    __syncthreads();

    // ---- epilogue: bias+relu+amax in regs, stage C in LDS [128][136], coalesced store ----
    f16* cst = lds;   // aliases buffers; safe after barrier
    float am[16];
    #pragma unroll
    for (int i = 0; i < 16; ++i) am[i] = 0.0f;
    #pragma unroll
    for (int n = 0; n < 4; ++n) {
        const int colB = wc + n * 16 + l15;
        const float bcol = bias[n0 + colB];
        #pragma unroll
        for (int m = 0; m < 4; ++m) {
            #pragma unroll
            for (int r2 = 0; r2 < 4; ++r2) {
                const int rowB = wr + m * 16 + (l4 << 2) + r2;
                float v = acc[m][n][r2] * (1.0f / 512.0f) + bcol * rsi[rowB];
                v = fmaxf(v, 0.0f);
                am[m * 4 + r2] = fmaxf(am[m * 4 + r2], v);
                cst[rowB * 136 + colB] = (f16)v;
            }
        }
    }
    __syncthreads();
    {
        f16* Cw; int csub;
        if (n0 < CB) { Cw = c0; csub = n0; } else { Cw = c1; csub = n0 - CB; }
        #pragma unroll
        for (int i = 0; i < 8; ++i) {
            int rowB = wid * 32 + i * 4 + l4;
            f16x8 vv = *(const f16x8*)&cst[rowB * 136 + l15 * 8];
            *(f16x8*)&Cw[(size_t)(m0 + rowB) * CB + csub + l15 * 8] = vv;
        }
    }
    if (recAmax) {
        #pragma unroll
        for (int i = 0; i < 16; ++i) {
            float a = am[i];
            a = fmaxf(a, __shfl_xor(a, 1));
            a = fmaxf(a, __shfl_xor(a, 2));
            a = fmaxf(a, __shfl_xor(a, 4));
            a = fmaxf(a, __shfl_xor(a, 8));
            if (l15 == 0) {
                int rowB = wr + (i >> 2) * 16 + (l4 << 2) + (i & 3);
                atomicMax((unsigned int*)&amaxR[rsOff + m0 + rowB],
                          __float_as_uint(a * rss[rowB]));
            }
        }
    }
}

// ---- pooling stage 1: deterministic segmented partial sums ----
__global__ __launch_bounds__(256) void pool1_k(
    const f16* __restrict__ h00, const f16* __restrict__ h01,
    const f16* __restrict__ h10, const f16* __restrict__ h11,
    const float* __restrict__ rs,
    const int* __restrict__ goff, float* __restrict__ partial, int half) {
    int g = blockIdx.x, c = blockIdx.y, s = blockIdx.z;
    int t = threadIdx.x;
    int col = c * 256 + t;
    int cb = col >= CB;
    int cc = cb ? col - CB : col;
    int i0 = goff[g], i1 = goff[g + 1];
    int len = i1 - i0;
    int s0 = i0 + (int)(((long long)len * s) / PSEG);
    int s1 = i0 + (int)(((long long)len * (s + 1)) / PSEG);
    float a = 0.0f;
    for (int i = s0; i < s1; ++i) {
        const f16* base = (i < half) ? (cb ? h10 : h00) : (cb ? h11 : h01);
        int r = (i < half) ? i : i - half;
        a += (float)base[(size_t)r * CB + cc] * rs[i];
    }
    partial[((size_t)(g * PSEG + s)) * HID + col] = a;
}

// ---- pooling stage 2: fixed-order sum of PSEG partials ----
__global__ __launch_bounds__(256) void pool2_k(const float* __restrict__ partial,
                                               float shift, float* __restrict__ pooled) {
    int g = blockIdx.x;
    int col = blockIdx.y * 256 + threadIdx.x;
    float a = 0.0f;
    #pragma unroll
    for (int s = 0; s < PSEG; ++s)
        a += partial[((size_t)(g * PSEG + s)) * HID + col];
    pooled[g * HID + col] = a * shift;
}

__global__ __launch_bounds__(512) void final_mm_k(const float* __restrict__ pooled,
                                                  const int* __restrict__ goff,
                                                  const float* __restrict__ Wf,
                                                  const float* __restrict__ bf,
                                                  float* __restrict__ out) {
    __shared__ float ps[HID];
    int g = blockIdx.x;
    int t = threadIdx.x;
    float inv = 1.0f / fmaxf((float)(goff[g + 1] - goff[g]), 1.0f);
    for (int k = t; k < HID; k += 512) ps[k] = pooled[g * HID + k] * inv;
    __syncthreads();
    float acc = bf[t];
    for (int k = 0; k < HID; ++k) acc += ps[k] * Wf[(size_t)k * EMB + t];
    out[(size_t)g * EMB + t] = acc;
}

__global__ void sentinel_k(float* __restrict__ out, int n, float v) {
    int i = blockIdx.x * 256 + threadIdx.x;
    if (i < n) out[i] = v;
}

// ---------------- launch ----------------
extern "C" void kernel_launch(void* const* d_in, const int* in_sizes, int n_in,
                              void* d_out, int out_size, void* d_ws, size_t ws_size,
                              hipStream_t stream) {
    const float* x    = (const float*)d_in[0];
    const int*   ei   = (const int*)d_in[1];
    const int*   batch= (const int*)d_in[2];
    const float* Wp   = (const float*)d_in[3];
    const float* bp   = (const float*)d_in[4];
    const float* W1   = (const float*)d_in[5];
    const float* b1   = (const float*)d_in[6];
    const float* W2   = (const float*)d_in[7];
    const float* b2   = (const float*)d_in[8];
    const float* Wf   = (const float*)d_in[9];
    const float* bf   = (const float*)d_in[10];
    float* out = (float*)d_out;

    const int nreal = in_sizes[0] / FIN;              // 100000
    const int E     = in_sizes[1] / 2;                // 200000
    const int npad  = ((nreal + 255) / 256) * 256;    // 100352
    const int half  = npad / 2;                       // 50176 (392 tiles of 128)
    const size_t slotsz = (size_t)half * CB;          // f16 elements per slot

    char* p = (char*)d_ws;
    auto alloc = [&](size_t bytes) -> char* {
        char* r = p; p += (bytes + 511) & ~(size_t)511; return r;
    };
    f16* slot[6];
    for (int i = 0; i < 6; ++i) slot[i] = (f16*)alloc(slotsz * sizeof(f16));
    f16*   wt   = (f16*)  alloc((size_t)2 * HID * HID * sizeof(f16));
    float* rsA  = (float*)alloc((size_t)npad * sizeof(float));
    float* rsB  = (float*)alloc((size_t)npad * sizeof(float));
    float* amaxR= (float*)alloc((size_t)npad * sizeof(float));
    int*   rp   = (int*)  alloc((size_t)(npad + 1) * sizeof(int));
    int*   csr  = (int*)  alloc((size_t)E * sizeof(int));
    float* wp1  = (float*)alloc((size_t)6 * HID * sizeof(float));
    int*   goff = (int*)  alloc((size_t)(NG + 1) * sizeof(int));
    float* pooled = (float*)alloc((size_t)NG * HID * sizeof(float));
    float* partial = (float*)alloc((size_t)NG * PSEG * HID * sizeof(float));
    char*  zstart = p;
    int*   deg  = (int*)  alloc((size_t)npad * sizeof(int));
    int*   cur  = (int*)  alloc((size_t)npad * sizeof(int));
    size_t zbytes = (size_t)(p - zstart);
    size_t need  = (size_t)(p - (char*)d_ws);

    if (need > ws_size) {
        sentinel_k<<<(out_size + 255) / 256, 256, 0, stream>>>(out, out_size, (float)(ws_size >> 20));
        return;
    }

    hipMemsetAsync(zstart, 0, zbytes, stream);

    count_deg_k  <<<(E + 255) / 256, 256, 0, stream>>>(ei, deg, E);
    goff_k       <<<1, 128, 0, stream>>>(batch, goff, nreal);
    scan_rowptr_k<<<1, 1024, 0, stream>>>(deg, rp, cur, nreal);
    scatter_k    <<<(E + 255) / 256, 256, 0, stream>>>(ei, cur, csr, E);
    sort_csr_k   <<<(nreal + 255) / 256, 256, 0, stream>>>(rp, csr, nreal);

    make_wp1_k<<<(HID + 255) / 256, 256, 0, stream>>>(Wp, bp, W1, wp1);

    // h slots: h00,h01 = col0 halves; h10,h11 = col1 halves; f0,f1 spare
    f16 *h00 = slot[0], *h01 = slot[1], *h10 = slot[2], *h11 = slot[3];
    f16 *f0 = slot[4], *f1 = slot[5];

    fused_l0_k<<<npad / 4, 256, 0, stream>>>(x, rp, csr, wp1, b1, h00, h01, h10, h11, rsA, nreal, half);

    const int nwg = (half / 128) * (HID / 128);   // 392*6 = 2352

    // layer 0 second matmul (W2[0]): row-half rotation, records amax
    convert_layer_k<<<dim3(HID / 64, HID / 64, 2), 256, 0, stream>>>(W1, W2, wt);
    hipMemsetAsync(amaxR, 0, (size_t)npad * sizeof(float), stream);
    gemm_seg_k<<<nwg, 256, 0, stream>>>(h00, h10, f0, f1, rsA, 0, 1.0f,
                                        wt + (size_t)HID * HID, b2, amaxR, 1);
    gemm_seg_k<<<nwg, 256, 0, stream>>>(h01, h11, h00, h10, rsA, half, 1.0f,
                                        wt + (size_t)HID * HID, b2, amaxR, 1);
    { f16 *n00 = f0, *n10 = f1, *n01 = h00, *n11 = h10, *nf0 = h01, *nf1 = h11;
      h00 = n00; h10 = n10; h01 = n01; h11 = n11; f0 = nf0; f1 = nf1; }

    float* rcur = rsA;
    float  shift = 8.0f;   // stored h = true / (rcur * shift)

    for (int l = 1; l < NL; ++l) {
        convert_layer_k<<<dim3(HID / 64, HID / 64, 2), 256, 0, stream>>>(
            W1 + (size_t)l * HID * HID, W2 + (size_t)l * HID * HID, wt);
        float* rnew = (rcur == rsA) ? rsB : rsA;
        aggscale_k<<<(npad + 255) / 256, 256, 0, stream>>>(amaxR, rp, csr, rnew, nreal, npad);
        // agg col0: (h00,h01) -> (f0,f1); agg col1: (h10,h11) -> (h00,h01)
        aggcol_k<<<npad / 8, 256, 0, stream>>>(h00, h01, f0, f1, rcur, shift, rnew, rp, csr, nreal, half);
        aggcol_k<<<npad / 8, 256, 0, stream>>>(h10, h11, h00, h01, rcur, shift, rnew, rp, csr, nreal, half);
        f16 *g00 = f0, *g01 = f1, *g10 = h00, *g11 = h01, *x0 = h10, *x1 = h11;
        // GEMM1 (W1_l): half0 in(g00,g10)->out(x0,x1); half1 in(g01,g11)->out(g00,g10)
        gemm_seg_k<<<nwg, 256, 0, stream>>>(g00, g10, x0, x1, rnew, 0, 1.0f,
                                            wt, b1 + (size_t)l * HID, amaxR, 0);
        gemm_seg_k<<<nwg, 256, 0, stream>>>(g01, g11, g00, g10, rnew, half, 1.0f,
                                            wt, b1 + (size_t)l * HID, amaxR, 0);
        f16 *z00 = x0, *z10 = x1, *z01 = g00, *z11 = g10;   // free: g01,g11
        // GEMM2 (W2_l): records amax
        hipMemsetAsync(amaxR, 0, (size_t)npad * sizeof(float), stream);
        gemm_seg_k<<<nwg, 256, 0, stream>>>(z00, z10, g01, g11, rnew, 0, 8.0f,
                                            wt + (size_t)HID * HID, b2 + (size_t)l * HID, amaxR, 1);
        gemm_seg_k<<<nwg, 256, 0, stream>>>(z01, z11, z00, z10, rnew, half, 8.0f,
                                            wt + (size_t)HID * HID, b2 + (size_t)l * HID, amaxR, 1);
        h00 = g01; h10 = g11; h01 = z00; h11 = z10; f0 = g00; f1 = g10;
        rcur = rnew;
        shift = 64.0f;
    }

    pool1_k<<<dim3(NG, HID / 256, PSEG), 256, 0, stream>>>(h00, h01, h10, h11, rcur, goff, partial, half);
    pool2_k<<<dim3(NG, HID / 256), 256, 0, stream>>>(partial, shift, pooled);
    final_mm_k<<<NG, 512, 0, stream>>>(pooled, goff, Wf, bf, out);
}